// Round 13
// baseline (800.832 us; speedup 1.0000x reference)
//
#include <hip/hip_runtime.h>
#include <hip/hip_bf16.h>
#include <math.h>

#define HID 128
#define NH  4
#define HD  32
#define FFD 512
#define RR  8
#define SCAN_B 1024
#define NB_SH 6              // 64 dst nodes per scatter bucket

typedef __attribute__((ext_vector_type(8))) short bf16x8;
typedef __attribute__((ext_vector_type(4))) float f32x4;
typedef unsigned short u16;
typedef unsigned long long u64;

static __device__ __forceinline__ float bf2f(u16 u) {
    union { unsigned int i; float f; } v; v.i = ((unsigned int)u) << 16; return v.f;
}
static __device__ __forceinline__ u16 f2bf(float f) {
    union { float f; unsigned int i; } v; v.f = f;
    unsigned int x = v.i;
    return (u16)((x + 0x7fffu + ((x >> 16) & 1u)) >> 16);
}

__global__ void zeroout_kernel(float* out, int n) {
    int i = blockIdx.x * 256 + threadIdx.x;
    if (i < n) out[i] = 0.f;
}

// zero deg2 (NN*RR), bcnt (NBK*16); acc only if zacc (multi-pass fallback)
__global__ void init_kernel(float* acc, int* deg2, int* bcnt, int NN, int NBK, int zacc) {
    int i = blockIdx.x * 256 + threadIdx.x;
    if (zacc && i < NN * HID) acc[i] = 0.f;
    if (i < NN * RR) deg2[i] = 0;
    if (i < NBK * 16) bcnt[i] = 0;
}

// ---------------------------------------------------------------------------
// Per-row LayerNorm stats (fp32 input).
// ---------------------------------------------------------------------------
__global__ void stats_kernel(const float* in, float* mu, float* rs, int NN) {
    int row = blockIdx.x * 4 + (threadIdx.x >> 6);
    int lane = threadIdx.x & 63;
    if (row >= NN) return;
    const float* p = in + (size_t)row * HID;
    float v0 = p[lane], v1 = p[lane + 64];
    float s = v0 + v1;
    #pragma unroll
    for (int o = 32; o > 0; o >>= 1) s += __shfl_xor(s, o, 64);
    float m = s * (1.0f / HID);
    float d0 = v0 - m, d1 = v1 - m;
    float q = d0 * d0 + d1 * d1;
    #pragma unroll
    for (int o = 32; o > 0; o >>= 1) q += __shfl_xor(q, o, 64);
    if (lane == 0) { mu[row] = m; rs[row] = rsqrtf(q * (1.0f / HID) + 1e-5f); }
}

// ---------------------------------------------------------------------------
// LN -> bf16 materialization (one thread per 8 elements).
// ---------------------------------------------------------------------------
__global__ void hnorm_kernel(const float* in, const float* mu, const float* rs,
                             const float* lw, const float* lb, u16* out, int NN) {
    int idx = blockIdx.x * 256 + threadIdx.x;
    if (idx >= NN * (HID / 8)) return;
    int row = idx >> 4;            // 16 chunks of 8 per row
    int k0 = (idx & 15) * 8;
    float m = mu[row], r = rs[row];
    const float* p = in + (size_t)row * HID + k0;
    float4 a0 = *(const float4*)p, a1 = *(const float4*)(p + 4);
    float4 w0 = *(const float4*)(lw + k0), w1 = *(const float4*)(lw + k0 + 4);
    float4 b0 = *(const float4*)(lb + k0), b1 = *(const float4*)(lb + k0 + 4);
    bf16x8 o;
    o[0] = (short)f2bf((a0.x - m) * r * w0.x + b0.x);
    o[1] = (short)f2bf((a0.y - m) * r * w0.y + b0.y);
    o[2] = (short)f2bf((a0.z - m) * r * w0.z + b0.z);
    o[3] = (short)f2bf((a0.w - m) * r * w0.w + b0.w);
    o[4] = (short)f2bf((a1.x - m) * r * w1.x + b1.x);
    o[5] = (short)f2bf((a1.y - m) * r * w1.y + b1.y);
    o[6] = (short)f2bf((a1.z - m) * r * w1.z + b1.z);
    o[7] = (short)f2bf((a1.w - m) * r * w1.w + b1.w);
    *(bf16x8*)(out + (size_t)row * HID + k0) = o;
}

// ---------------------------------------------------------------------------
// Transpose fp32 weights to bf16 [n][k] for contiguous GEMM B-fragments.
// ---------------------------------------------------------------------------
__global__ void transpose_kernel(const float* w, const float* rootw,
                                 const float* w1, const float* w2,
                                 u16* WT, u16* rootT, u16* W1T, u16* W2T, int R) {
    int i = blockIdx.x * 256 + threadIdx.x;
    int nW = R * HID * HID;
    if (i < nW) {
        int r = i / (HID * HID); int rem = i % (HID * HID);
        int n = rem / HID, k = rem % HID;
        WT[i] = f2bf(w[r * HID * HID + k * HID + n]);
    } else if (i < nW + HID * HID) {
        int j = i - nW; int n = j / HID, k = j % HID;
        rootT[j] = f2bf(rootw[k * HID + n]);
    } else if (i < nW + HID * HID + FFD * HID) {
        int j = i - nW - HID * HID; int n = j / HID, k = j % HID;
        W1T[j] = f2bf(w1[k * FFD + n]);
    } else if (i < nW + HID * HID + FFD * HID + HID * FFD) {
        int j = i - nW - HID * HID - FFD * HID; int n = j / FFD, k = j % FFD;
        W2T[j] = f2bf(w2[k * HID + n]);
    }
}

// ---------------------------------------------------------------------------
// Fold W_r into attention vectors:  Vsd[n'][k], n' = r*4+h (src) / 32+r*4+h
// (dst).  Vs[r,h,k] = sum_d W[r][k][h*32+d] * att[h*32+d].
// ---------------------------------------------------------------------------
__global__ void vsd_kernel(const float* w, const float* att_src, const float* att_dst,
                           u16* Vsd, int R) {
    int idx = blockIdx.x * 256 + threadIdx.x;
    if (idx >= 64 * HID) return;
    int np = idx >> 7, k = idx & 127;
    int isDst = np >> 5, rh = np & 31, r = rh >> 2, h = rh & 3;
    const float* av = (isDst ? att_dst : att_src) + h * HD;
    const float* wp = w + (size_t)r * HID * HID + (size_t)k * HID + h * HD;
    float s = 0.f;
    #pragma unroll
    for (int d = 0; d < HD; d++) s += wp[d] * av[d];
    Vsd[idx] = f2bf(s);
}

__global__ void ae_kernel(const float* emb, const float* att_edge, float* ae, int R) {
    int i = threadIdx.x;
    if (i >= R * NH) return;
    int r = i >> 2, h = i & 3;
    float s = 0.f;
    #pragma unroll
    for (int d = 0; d < HD; d++)
        s += emb[r * HID + h * HD + d] * att_edge[h * HD + d];
    ae[i] = s;
}

// ---------------------------------------------------------------------------
// Register-resident-A GEMM for K=128, bf16 out (used for FFN1).
// EPI 0: raw bf16    EPI 2: +b1, exact gelu -> bf16
// ---------------------------------------------------------------------------
template <int EPI>
__global__ __launch_bounds__(256)
void gemmy_kernel(const u16* Araw, const u16* BT, u16* Cout, const float* bias,
                  int M, int N, int aOff, int cOff, int ytiles) {
    int w = threadIdx.x >> 6, lane = threadIdx.x & 63;
    int l15 = lane & 15, quad = lane >> 4;
    int m0 = blockIdx.x * 64 + w * 16;
    int rowA = m0 + l15; if (rowA > M - 1) rowA = M - 1;
    const u16* ap = Araw + (size_t)(aOff + rowA) * HID + quad * 8;
    bf16x8 a[4];
    #pragma unroll
    for (int kk = 0; kk < 4; kk++) a[kk] = *(const bf16x8*)(ap + kk * 32);

    __shared__ u16 tile[64][72];
    int rl2 = threadIdx.x >> 3, seg = threadIdx.x & 7;
    int ybase = blockIdx.y * ytiles;
    for (int yi = 0; yi < ytiles; yi++) {
        int n0 = (ybase + yi) * 64;
        f32x4 accr[4] = {};
        #pragma unroll
        for (int kk = 0; kk < 4; kk++) {
            #pragma unroll
            for (int t = 0; t < 4; t++) {
                const u16* bp = BT + (size_t)(n0 + t * 16 + l15) * HID + quad * 8 + kk * 32;
                bf16x8 bfrag = *(const bf16x8*)bp;
                accr[t] = __builtin_amdgcn_mfma_f32_16x16x32_bf16(a[kk], bfrag, accr[t], 0, 0, 0);
            }
        }
        if (yi > 0) __syncthreads();        // prior iter's LDS reads complete
        #pragma unroll
        for (int t = 0; t < 4; t++) {
            int col = n0 + t * 16 + l15;
            #pragma unroll
            for (int j = 0; j < 4; j++) {
                float v = accr[t][j];
                if constexpr (EPI == 2) {
                    v += bias[col];
                    v = 0.5f * v * (1.0f + erff(v * 0.70710678118654752f));
                }
                tile[w * 16 + quad * 4 + j][t * 16 + l15] = f2bf(v);
            }
        }
        __syncthreads();
        #pragma unroll
        for (int h = 0; h < 2; h++) {
            int rl = h * 32 + rl2;
            int row = blockIdx.x * 64 + rl;
            if (row < M) {
                u16* dst = Cout + (size_t)(cOff + row) * N + n0 + seg * 8;
                *(bf16x8*)dst = *(const bf16x8*)&tile[rl][seg * 8];
            }
        }
    }
}

// ---------------------------------------------------------------------------
// General MFMA GEMM, 64x64 block tile, 4 waves, 16x16x32 bf16.
// AM 0: A = fp32 + LN affine -> bf16      AM 2: A = bf16 raw
// EPI 0: raw bf16 (LDS-staged, line-contiguous stores)       [fallback path]
// EPI 1: + acc*invden + bias, elu, + x(fp32) -> FP32 store
// EPI 2: + b1, exact gelu -> bf16 (LDS-staged)               [fallback path]
// EPI 3: + b2 + resid(fp32) -> FP32 store
// EPI 5: split fp32 store: col<32 -> as[row][col], col>=32 -> ad[row][col-32]
// ---------------------------------------------------------------------------
template <int AM, int EPI>
__global__ __launch_bounds__(256)
void gemm_kernel(const void* Araw, const float* mu, const float* rs,
                 const float* lw, const float* lb,
                 const u16* BT, void* Cout, const float* bias,
                 const float* acc, const float* xin, const float* invden,
                 int M, int N, int K, int aOff, int cOff) {
    int w = threadIdx.x >> 6, lane = threadIdx.x & 63;
    int l15 = lane & 15, quad = lane >> 4;
    int m0 = blockIdx.x * 64 + w * 16;
    int n0 = blockIdx.y * 64;
    int rowA = m0 + l15; if (rowA > M - 1) rowA = M - 1;
    int gA = aOff + rowA;
    float muv = 0.f, rsv = 0.f;
    if (AM != 2) { muv = mu[gA]; rsv = rs[gA]; }

    f32x4 accr[4] = {};
    for (int kc = 0; kc < K; kc += 32) {
        bf16x8 a;
        if (AM == 0) {
            const float* ap = (const float*)Araw + (size_t)gA * K + quad * 8 + kc;
            float4 xa0 = *(const float4*)(ap);
            float4 xa1 = *(const float4*)(ap + 4);
            float4 w0 = *(const float4*)(lw + kc + quad * 8);
            float4 w1v = *(const float4*)(lw + kc + quad * 8 + 4);
            float4 b0 = *(const float4*)(lb + kc + quad * 8);
            float4 b1v = *(const float4*)(lb + kc + quad * 8 + 4);
            a[0] = (short)f2bf((xa0.x - muv) * rsv * w0.x + b0.x);
            a[1] = (short)f2bf((xa0.y - muv) * rsv * w0.y + b0.y);
            a[2] = (short)f2bf((xa0.z - muv) * rsv * w0.z + b0.z);
            a[3] = (short)f2bf((xa0.w - muv) * rsv * w0.w + b0.w);
            a[4] = (short)f2bf((xa1.x - muv) * rsv * w1v.x + b1v.x);
            a[5] = (short)f2bf((xa1.y - muv) * rsv * w1v.y + b1v.y);
            a[6] = (short)f2bf((xa1.z - muv) * rsv * w1v.z + b1v.z);
            a[7] = (short)f2bf((xa1.w - muv) * rsv * w1v.w + b1v.w);
        } else {
            const u16* ap = (const u16*)Araw + (size_t)gA * K + quad * 8 + kc;
            a = *(const bf16x8*)ap;
        }
        #pragma unroll
        for (int t = 0; t < 4; t++) {
            const u16* bp = BT + (size_t)(n0 + t * 16 + l15) * K + quad * 8 + kc;
            bf16x8 bfrag = *(const bf16x8*)bp;
            accr[t] = __builtin_amdgcn_mfma_f32_16x16x32_bf16(a, bfrag, accr[t], 0, 0, 0);
        }
    }

    if constexpr (EPI == 0 || EPI == 2) {
        __shared__ u16 tile[64][72];
        #pragma unroll
        for (int t = 0; t < 4; t++) {
            int col = n0 + t * 16 + l15;
            #pragma unroll
            for (int j = 0; j < 4; j++) {
                float v = accr[t][j];
                if (EPI == 2) {
                    v += bias[col];
                    v = 0.5f * v * (1.0f + erff(v * 0.70710678118654752f));
                }
                tile[w * 16 + quad * 4 + j][t * 16 + l15] = f2bf(v);
            }
        }
        __syncthreads();
        int rl2 = threadIdx.x >> 3, seg = threadIdx.x & 7;
        #pragma unroll
        for (int h = 0; h < 2; h++) {
            int rl = h * 32 + rl2;
            int row = blockIdx.x * 64 + rl;
            if (row < M) {
                u16* dst = (u16*)Cout + (size_t)(cOff + row) * N + n0 + seg * 8;
                *(bf16x8*)dst = *(const bf16x8*)&tile[rl][seg * 8];
            }
        }
    } else {
        #pragma unroll
        for (int t = 0; t < 4; t++) {
            int col = n0 + t * 16 + l15;
            #pragma unroll
            for (int j = 0; j < 4; j++) {
                int row = m0 + quad * 4 + j;
                if (row < M) {
                    float v = accr[t][j];
                    int grow = cOff + row;
                    size_t off = (size_t)grow * N + col;
                    if (EPI == 1) {
                        float msg = acc[(size_t)grow * HID + col]
                                  * invden[(size_t)grow * NH + (col >> 5)];
                        float o = v + msg + bias[col];
                        o = o > 0.f ? o : expm1f(o);
                        ((float*)Cout)[off] = xin[off] + o;
                    } else if (EPI == 3) {
                        ((float*)Cout)[off] = v + bias[col] + xin[off];
                    } else if (EPI == 5) {
                        float* tab = (float*)Cout;
                        if (col < 32) tab[(size_t)grow * 32 + col] = v;
                        else tab[(size_t)(M + grow) * 32 + (col - 32)] = v;
                    }
                }
            }
        }
    }
}

// ---------------------------------------------------------------------------
// CSR grouped by (dst, rel): histogram over NN*RR -> scan -> bucketed scatter.
// ---------------------------------------------------------------------------
__global__ void deg_kernel(const int* ei, const int* et, int* deg2, int E, int NN) {
    int e = blockIdx.x * 256 + threadIdx.x;
    if (e >= E) return;
    int s = ei[e], d = ei[E + e], r = et[e];
    if ((unsigned)d < (unsigned)NN && (unsigned)r < (unsigned)RR &&
        (unsigned)s < (unsigned)NN)
        atomicAdd(&deg2[d * RR + r], 1);
}

__global__ void scan1_kernel(const int* in, int* out, int* bsum, int n) {
    __shared__ int buf[SCAN_B];
    int i = blockIdx.x * SCAN_B + threadIdx.x;
    int v = (i < n) ? in[i] : 0;
    buf[threadIdx.x] = v;
    __syncthreads();
    for (int s = 1; s < SCAN_B; s <<= 1) {
        int t = (threadIdx.x >= s) ? buf[threadIdx.x - s] : 0;
        __syncthreads();
        buf[threadIdx.x] += t;
        __syncthreads();
    }
    if (i < n) out[i] = buf[threadIdx.x] - v;
    if (threadIdx.x == SCAN_B - 1) bsum[blockIdx.x] = buf[SCAN_B - 1];
}

__global__ void scan2_kernel(int* bsum, int nb) {
    __shared__ int buf[SCAN_B];
    int v = (threadIdx.x < nb) ? bsum[threadIdx.x] : 0;
    buf[threadIdx.x] = v;
    __syncthreads();
    for (int s = 1; s < SCAN_B; s <<= 1) {
        int t = (threadIdx.x >= s) ? buf[threadIdx.x - s] : 0;
        __syncthreads();
        buf[threadIdx.x] += t;
        __syncthreads();
    }
    if (threadIdx.x < nb) bsum[threadIdx.x] = buf[threadIdx.x] - v;
    if (threadIdx.x == SCAN_B - 1) bsum[nb] = buf[SCAN_B - 1];
}

__global__ void scan3_kernel(int* out, int* curpos, const int* bsum, int n, int nb) {
    int i = blockIdx.x * SCAN_B + threadIdx.x;
    if (i < n) {
        int o = out[i] + bsum[blockIdx.x];
        out[i] = o; curpos[i] = o;
    }
    if (i == 0) out[n] = bsum[nb];
}

// Phase A: append (d | r<<24|s) into the dst-bucket's exact CSR region.
__global__ void fillA_kernel(const int* ei, const int* et, const int* offs2,
                             int* bcnt, u64* tmp, int E, int NN) {
    int e = blockIdx.x * 256 + threadIdx.x;
    if (e >= E) return;
    int s = ei[e], d = ei[E + e], r = et[e];
    if ((unsigned)d >= (unsigned)NN || (unsigned)r >= (unsigned)RR ||
        (unsigned)s >= (unsigned)NN) return;
    int b = d >> NB_SH;
    int base = offs2[(b << NB_SH) * RR];
    int pos = atomicAdd(&bcnt[b * 16], 1);        // 64B-padded counter
    tmp[base + pos] = ((u64)d << 32) | (unsigned)((r << 24) | s);
}

// Phase B: one workgroup per bucket; scatter within the bucket's small region.
__global__ void fillB_kernel(const u64* tmp, const int* offs2,
                             int* curpos2, int* rs_arr, int NN) {
    int b = blockIdx.x;
    int n0 = b << NB_SH;
    int n1 = n0 + (1 << NB_SH); if (n1 > NN) n1 = NN;
    int base = offs2[n0 * RR];
    int end  = offs2[n1 * RR];
    for (int i = base + threadIdx.x; i < end; i += 256) {
        u64 t = tmp[i];
        int d = (int)(t >> 32);
        unsigned v = (unsigned)t;
        int r = v >> 24;
        int pos = atomicAdd(&curpos2[d * RR + r], 1);
        rs_arr[pos] = (int)v;
    }
}

// ---------------------------------------------------------------------------
// Softmax weights: ONE WAVE per dst node (lanes = 16 edge-slots x 4 heads).
// ---------------------------------------------------------------------------
__global__ void wgt_kernel(const int* offs2, const int* rs_arr,
                           const float* asad, const float* ae,
                           float* wgt, float* invden, int NN, int E) {
    int n = blockIdx.x * 4 + (threadIdx.x >> 6);
    if (n >= NN) return;
    int lane = threadIdx.x & 63;
    int el = lane >> 2, h = lane & 3;
    int p0 = offs2[n * RR], p1 = offs2[n * RR + RR];
    const float* ad = asad + (size_t)NN * 32;
    float base[RR];
    #pragma unroll
    for (int r = 0; r < RR; r++)
        base[r] = ad[(size_t)n * 32 + r * 4 + h] + ae[r * 4 + h];
    float mx = -1e30f;
    for (int p = p0 + el; p < p1; p += 16) {
        unsigned v = (unsigned)rs_arr[p];
        int r = v >> 24, s = v & 0xFFFFFF;
        float a = asad[(size_t)s * 32 + r * 4 + h] + base[r];
        a = a > 0.f ? a : 0.2f * a;
        wgt[(size_t)p * NH + h] = a;
        mx = fmaxf(mx, a);
    }
    #pragma unroll
    for (int o = 4; o < 64; o <<= 1) mx = fmaxf(mx, __shfl_xor(mx, o, 64));
    float den = 0.f;
    for (int p = p0 + el; p < p1; p += 16) {
        float ex = __expf(wgt[(size_t)p * NH + h] - mx);
        wgt[(size_t)p * NH + h] = ex;
        den += ex;
    }
    #pragma unroll
    for (int o = 4; o < 64; o <<= 1) den += __shfl_xor(den, o, 64);
    if (el == 0) invden[n * NH + h] = 1.0f / (den + 1e-16f);
}

// ---------------------------------------------------------------------------
// FUSED message kernel: aggregate-then-project, PER-HEAD (the attention
// weight is indexed by the OUTPUT channel's head; W_r mixes all inputs, so
// we need 4 head-planes S_h[d][k] = sum_e wgt_e[h]*hnorm[s_e][k]).
// One block (8 waves) per 64-node bucket.  Per rel r: build all 4 planes in
// LDS (64KB, byte-XOR swizzled vs 256B-stride bank camping), then
// acc64x128 += S_{head(col)} x W_r via MFMA (head(col) = coltile>>1).
// Gathers hit the L2/L3-resident hbuf (12.8MB); no 102MB intermediate.
// ---------------------------------------------------------------------------
__global__ __launch_bounds__(512)
void msgf_kernel(const int* offs2, const int* rs_arr, const float* wgt,
                 const u16* hbuf, const u16* WTw, float* acc, int NN) {
    __shared__ u16 S[4 * 64 * HID];   // 65536 B: 4 head-planes of [64][128]
    char* Sb = (char*)S;
    int tid = threadIdx.x;
    int wv = tid >> 6, lane = tid & 63;
    int l15 = lane & 15, quad = lane >> 4;
    int n0b = blockIdx.x << NB_SH;
    int tm = wv & 3;              // MFMA row-tile
    int cb = (wv >> 2) * 4;       // MFMA col-tile base

    f32x4 accr[4] = {};
    for (int r = 0; r < RR; r++) {
        // aggregate: wave wv owns dsts [wv*8, wv*8+8); lane owns channel
        // pair c2=2*lane; write ALL slots (zeros when no edges / n>=NN).
        #pragma unroll 1
        for (int dd = 0; dd < 8; dd++) {
            int d = wv * 8 + dd;
            int n = n0b + d;
            float a00 = 0.f, a01 = 0.f, a10 = 0.f, a11 = 0.f;
            float a20 = 0.f, a21 = 0.f, a30 = 0.f, a31 = 0.f;
            if (n < NN) {
                int p0 = offs2[n * RR + r], p1 = offs2[n * RR + r + 1];
                for (int p = p0; p < p1; p++) {
                    unsigned v = (unsigned)rs_arr[p];
                    unsigned z = *(const unsigned*)(hbuf
                                    + (size_t)(v & 0xFFFFFFu) * HID + (lane << 1));
                    float4 w4 = *(const float4*)(wgt + (size_t)p * NH);
                    float x0 = bf2f((u16)z), x1 = bf2f((u16)(z >> 16));
                    a00 += w4.x * x0; a01 += w4.x * x1;
                    a10 += w4.y * x0; a11 += w4.y * x1;
                    a20 += w4.z * x0; a21 += w4.z * x1;
                    a30 += w4.w * x0; a31 += w4.w * x1;
                }
            }
            int wb = (d << 8) + (lane << 2);      // byte off within a plane
            wb ^= (d & 7) << 4;                   // swizzle (involution)
            *(unsigned*)(Sb + wb)           = (unsigned)f2bf(a00) | ((unsigned)f2bf(a01) << 16);
            *(unsigned*)(Sb + 16384 + wb)   = (unsigned)f2bf(a10) | ((unsigned)f2bf(a11) << 16);
            *(unsigned*)(Sb + 32768 + wb)   = (unsigned)f2bf(a20) | ((unsigned)f2bf(a21) << 16);
            *(unsigned*)(Sb + 49152 + wb)   = (unsigned)f2bf(a30) | ((unsigned)f2bf(a31) << 16);
        }
        __syncthreads();
        // acc += S_{head} (64x128) x W_r; col-tile ctt uses head ctt>>1
        const u16* Wr = WTw + (size_t)r * HID * HID;
        int arow = tm * 16 + l15;
        #pragma unroll
        for (int ks = 0; ks < 4; ks++) {
            #pragma unroll
            for (int ct = 0; ct < 4; ct++) {
                int ctt = cb + ct;
                int hh = ctt >> 1;
                int rb = (hh << 14) + (arow << 8) + (ks << 6) + (quad << 4);
                rb ^= (arow & 7) << 4;
                bf16x8 afrag = *(const bf16x8*)(Sb + rb);
                const u16* bp = Wr + (size_t)(ctt * 16 + l15) * HID + ks * 32 + quad * 8;
                bf16x8 bfrag = *(const bf16x8*)bp;
                accr[ct] = __builtin_amdgcn_mfma_f32_16x16x32_bf16(afrag, bfrag, accr[ct], 0, 0, 0);
            }
        }
        __syncthreads();   // S reads done before next rel overwrites
    }
    // write unnormalized msg (invden applied in root-GEMM epilogue)
    #pragma unroll
    for (int ct = 0; ct < 4; ct++) {
        int col = (cb + ct) * 16 + l15;
        #pragma unroll
        for (int j = 0; j < 4; j++) {
            int row = tm * 16 + quad * 4 + j;
            int n = n0b + row;
            if (n < NN) acc[(size_t)n * HID + col] = accr[ct][j];
        }
    }
}

// ---------------------------------------------------------------------------
// Multi-pass fallback (nrel < RR): one block (128 thr) per dst node, RMW acc.
// ---------------------------------------------------------------------------
__global__ void msg2_kernel(const int* offs2, const int* rs_arr, const float* wgt,
                            const u16* xp, float* acc, int rc, int nrel, int ldx,
                            int NN, int E) {
    int n = blockIdx.x;
    int c = threadIdx.x, h = c >> 5;
    int p0 = offs2[n * RR + rc], p1 = offs2[n * RR + rc + nrel];
    if (p0 >= p1) return;
    float av = acc[(size_t)n * HID + c];
    for (int p = p0; p < p1; p++) {
        unsigned v = (unsigned)rs_arr[p];
        int r = (v >> 24) - rc;
        int s = v & 0xFFFFFF;
        av += wgt[(size_t)p * NH + h] * bf2f(xp[(size_t)s * ldx + r * HID + c]);
    }
    acc[(size_t)n * HID + c] = av;
}

// ---------------------------------------------------------------------------
extern "C" void kernel_launch(void* const* d_in, const int* in_sizes, int n_in,
                              void* d_out, int out_size, void* d_ws, size_t ws_size,
                              hipStream_t stream) {
    const float* x        = (const float*)d_in[0];
    const float* w        = (const float*)d_in[1];
    const float* rootw    = (const float*)d_in[2];
    const float* emb      = (const float*)d_in[3];
    const float* att_src  = (const float*)d_in[4];
    const float* att_dst  = (const float*)d_in[5];
    const float* att_edge = (const float*)d_in[6];
    const float* bias     = (const float*)d_in[7];
    const float* n1w      = (const float*)d_in[8];
    const float* n1b      = (const float*)d_in[9];
    const float* n2w      = (const float*)d_in[10];
    const float* n2b      = (const float*)d_in[11];
    const float* w1       = (const float*)d_in[12];
    const float* b1       = (const float*)d_in[13];
    const float* w2       = (const float*)d_in[14];
    const float* b2       = (const float*)d_in[15];
    const int* ei = (const int*)d_in[16];
    const int* et = (const int*)d_in[17];

    int NN = in_sizes[0] / HID;         // 50000
    int R  = in_sizes[1] / (HID * HID); // 8
    int E  = in_sizes[17];              // 800000
    int NR = NN * RR;
    int NBK = (NN + (1 << NB_SH) - 1) >> NB_SH;   // 782 buckets

    // ---- arena ------------------------------------------------------------
    char* p = (char*)d_ws;
    auto alloc = [&](size_t bytes) -> char* {
        char* q = p; p += (bytes + 255) & ~(size_t)255; return q;
    };
    int* offs2   = (int*)alloc((size_t)(NR + 1) * 4);
    int* rs_arr  = (int*)alloc((size_t)E * 4);
    u16* WTw   = (u16*)alloc((size_t)R * HID * HID * 2);
    u16* rootT = (u16*)alloc((size_t)HID * HID * 2);
    u16* W1T   = (u16*)alloc((size_t)FFD * HID * 2);
    u16* W2T   = (u16*)alloc((size_t)HID * FFD * 2);
    u16* Vsd   = (u16*)alloc((size_t)64 * HID * 2);
    float* ae  = (float*)alloc((size_t)R * NH * 4);
    float* mu1 = (float*)alloc((size_t)NN * 4);
    float* rs1 = (float*)alloc((size_t)NN * 4);
    float* mu2 = (float*)alloc((size_t)NN * 4);
    float* rs2 = (float*)alloc((size_t)NN * 4);
    float* asad   = (float*)alloc((size_t)NN * 64 * 4);   // as|ad tables; later hnorm
    float* invden = (float*)alloc((size_t)NN * NH * 4);
    float* wgt    = (float*)alloc((size_t)E * NH * 4);
    float* acc    = (float*)alloc((size_t)NN * HID * 4);

    // CSR-build scratch aliases the (not-yet-live) wgt buffer (12.8MB).
    int nbScan = (NR + SCAN_B - 1) / SCAN_B;
    int* deg2    = (int*)wgt;
    int* curpos2 = deg2 + NR;
    int* bsum    = curpos2 + NR;
    int* bcnt    = bsum + nbScan + 1;
    u64* tmp     = (u64*)(((size_t)(bcnt + NBK * 16) + 7) & ~(size_t)7);

    // scratch buffer: FFN intermediate u (and multi-rel fallback xp).
    size_t usedFixed = (size_t)(p - (char*)d_ws);
    int nrel = 1;
    for (int t = 8; t > 1; t >>= 1) {
        if (ws_size >= usedFixed + (size_t)NN * HID * t * 2 + 256) { nrel = t; break; }
    }
    u16* xp = (u16*)alloc((size_t)NN * HID * nrel * 2);
    u16* u_ch = xp;                   // alias: FFN intermediate
    u16* hbuf = (u16*)asad;           // alias: NN*64*4B == NN*128*2B exactly
    float* x2 = (float*)d_out;        // x2 lives in d_out until FFN2 overwrites

    size_t used = (size_t)(p - (char*)d_ws);
    if (used > ws_size) {
        zeroout_kernel<<<(out_size + 255) / 256, 256, 0, stream>>>((float*)d_out, out_size);
        return;
    }

    // ---- phase 0: init, stats, weights, CSR -------------------------------
    int single = (nrel == RR) ? 1 : 0;
    int initN = single ? (NR > NBK * 16 ? NR : NBK * 16) : NN * HID;
    init_kernel<<<(initN + 255) / 256, 256, 0, stream>>>(acc, deg2, bcnt, NN, NBK,
                                                         single ? 0 : 1);
    stats_kernel<<<(NN + 3) / 4, 256, 0, stream>>>(x, mu1, rs1, NN);
    int nT = R * HID * HID + HID * HID + FFD * HID + HID * FFD;
    transpose_kernel<<<(nT + 255) / 256, 256, 0, stream>>>(w, rootw, w1, w2,
                                                           WTw, rootT, W1T, W2T, R);
    vsd_kernel<<<(64 * HID + 255) / 256, 256, 0, stream>>>(w, att_src, att_dst, Vsd, R);
    ae_kernel<<<1, 64, 0, stream>>>(emb, att_edge, ae, R);
    deg_kernel<<<(E + 255) / 256, 256, 0, stream>>>(ei, et, deg2, E, NN);
    scan1_kernel<<<nbScan, SCAN_B, 0, stream>>>(deg2, offs2, bsum, NR);
    scan2_kernel<<<1, SCAN_B, 0, stream>>>(bsum, nbScan);
    scan3_kernel<<<nbScan, SCAN_B, 0, stream>>>(offs2, curpos2, bsum, NR, nbScan);
    fillA_kernel<<<(E + 255) / 256, 256, 0, stream>>>(ei, et, offs2, bcnt, tmp, E, NN);
    fillB_kernel<<<NBK, 256, 0, stream>>>(tmp, offs2, curpos2, rs_arr, NN);

    // ---- phase 1: ALL attention dot tables in ONE GEMM (split store) ------
    int gxN = (NN + 63) / 64;
    gemm_kernel<0, 5><<<dim3(gxN, 1), 256, 0, stream>>>(
        x, mu1, rs1, n1w, n1b, Vsd, asad,
        nullptr, nullptr, nullptr, nullptr, NN, 64, HID, 0, 0);

    // ---- phase 2: exact per-edge softmax (unnormalized), wave per node ----
    wgt_kernel<<<(NN + 3) / 4, 256, 0, stream>>>(
        offs2, rs_arr, asad, ae, wgt, invden, NN, E);

    // asad is dead; materialize LN1(x) as bf16 into the same buffer.
    hnorm_kernel<<<(NN * (HID / 8) + 255) / 256, 256, 0, stream>>>(
        x, mu1, rs1, n1w, n1b, hbuf, NN);

    // ---- phase 3: FUSED aggregate-then-project message pass ---------------
    if (single) {
        msgf_kernel<<<NBK, 512, 0, stream>>>(offs2, rs_arr, wgt, hbuf, WTw, acc, NN);
    } else {
        for (int rc = 0; rc < RR; rc += nrel) {
            gemm_kernel<2, 0><<<dim3(gxN, (HID * nrel) / 64), 256, 0, stream>>>(
                hbuf, nullptr, nullptr, nullptr, nullptr, WTw + (size_t)rc * HID * HID,
                xp, nullptr, nullptr, nullptr, nullptr, NN, HID * nrel, HID, 0, 0);
            msg2_kernel<<<NN, HID, 0, stream>>>(offs2, rs_arr, wgt, xp, acc,
                                                rc, nrel, HID * nrel, NN, E);
        }
    }

    // ---- phase 4: root gemm + msg*invden + bias + elu + residual -> x2 ----
    gemm_kernel<2, 1><<<dim3(gxN, HID / 64), 256, 0, stream>>>(
        hbuf, nullptr, nullptr, nullptr, nullptr, rootT, x2, bias, acc, x, invden,
        NN, HID, HID, 0, 0);

    // ---- phase 5: ln2 stats + hnorm2 + FFN ------------------------------
    stats_kernel<<<(NN + 3) / 4, 256, 0, stream>>>(x2, mu2, rs2, NN);
    hnorm_kernel<<<(NN * (HID / 8) + 255) / 256, 256, 0, stream>>>(
        x2, mu2, rs2, n2w, n2b, hbuf, NN);
    int nchunk = (nrel >= 4) ? 1 : (nrel == 2 ? 2 : 4);
    int NCH = (NN + nchunk - 1) / nchunk;
    for (int j = 0; j < nchunk; j++) {
        int r0 = j * NCH;
        int Mc = NN - r0; if (Mc > NCH) Mc = NCH;
        if (Mc <= 0) continue;
        int gxc = (Mc + 63) / 64;
        // FFN1 (K=128): reg-A GEMM, A read once per y-slice.
        gemmy_kernel<2><<<dim3(gxc, 2), 256, 0, stream>>>(
            hbuf, W1T, u_ch, b1, Mc, FFD, r0, 0, 4);
        gemm_kernel<2, 3><<<dim3(gxc, HID / 64), 256, 0, stream>>>(
            u_ch, nullptr, nullptr, nullptr, nullptr, W2T, (float*)d_out, b2,
            nullptr, x2, nullptr, Mc, HID, FFD, 0, r0);
    }
}

// Round 14
// 618.878 us; speedup vs baseline: 1.2940x; 1.2940x over previous
//
#include <hip/hip_runtime.h>
#include <hip/hip_bf16.h>
#include <math.h>

#define HID 128
#define NH  4
#define HD  32
#define FFD 512
#define RR  8
#define SCAN_B 1024
#define NB_SH 6              // 64 dst nodes per scatter bucket

typedef __attribute__((ext_vector_type(8))) short bf16x8;
typedef __attribute__((ext_vector_type(4))) float f32x4;
typedef unsigned short u16;
typedef unsigned long long u64;

static __device__ __forceinline__ float bf2f(u16 u) {
    union { unsigned int i; float f; } v; v.i = ((unsigned int)u) << 16; return v.f;
}
static __device__ __forceinline__ u16 f2bf(float f) {
    union { float f; unsigned int i; } v; v.f = f;
    unsigned int x = v.i;
    return (u16)((x + 0x7fffu + ((x >> 16) & 1u)) >> 16);
}

__global__ void zeroout_kernel(float* out, int n) {
    int i = blockIdx.x * 256 + threadIdx.x;
    if (i < n) out[i] = 0.f;
}

// zero deg2 (NN*RR), bcnt (NBK*16); acc only if zacc (multi-pass fallback)
__global__ void init_kernel(float* acc, int* deg2, int* bcnt, int NN, int NBK, int zacc) {
    int i = blockIdx.x * 256 + threadIdx.x;
    if (zacc && i < NN * HID) acc[i] = 0.f;
    if (i < NN * RR) deg2[i] = 0;
    if (i < NBK * 16) bcnt[i] = 0;
}

// ---------------------------------------------------------------------------
// Per-row LayerNorm stats (fp32 input).
// ---------------------------------------------------------------------------
__global__ void stats_kernel(const float* in, float* mu, float* rs, int NN) {
    int row = blockIdx.x * 4 + (threadIdx.x >> 6);
    int lane = threadIdx.x & 63;
    if (row >= NN) return;
    const float* p = in + (size_t)row * HID;
    float v0 = p[lane], v1 = p[lane + 64];
    float s = v0 + v1;
    #pragma unroll
    for (int o = 32; o > 0; o >>= 1) s += __shfl_xor(s, o, 64);
    float m = s * (1.0f / HID);
    float d0 = v0 - m, d1 = v1 - m;
    float q = d0 * d0 + d1 * d1;
    #pragma unroll
    for (int o = 32; o > 0; o >>= 1) q += __shfl_xor(q, o, 64);
    if (lane == 0) { mu[row] = m; rs[row] = rsqrtf(q * (1.0f / HID) + 1e-5f); }
}

// ---------------------------------------------------------------------------
// LN -> bf16 materialization (one thread per 8 elements).
// ---------------------------------------------------------------------------
__global__ void hnorm_kernel(const float* in, const float* mu, const float* rs,
                             const float* lw, const float* lb, u16* out, int NN) {
    int idx = blockIdx.x * 256 + threadIdx.x;
    if (idx >= NN * (HID / 8)) return;
    int row = idx >> 4;            // 16 chunks of 8 per row
    int k0 = (idx & 15) * 8;
    float m = mu[row], r = rs[row];
    const float* p = in + (size_t)row * HID + k0;
    float4 a0 = *(const float4*)p, a1 = *(const float4*)(p + 4);
    float4 w0 = *(const float4*)(lw + k0), w1 = *(const float4*)(lw + k0 + 4);
    float4 b0 = *(const float4*)(lb + k0), b1 = *(const float4*)(lb + k0 + 4);
    bf16x8 o;
    o[0] = (short)f2bf((a0.x - m) * r * w0.x + b0.x);
    o[1] = (short)f2bf((a0.y - m) * r * w0.y + b0.y);
    o[2] = (short)f2bf((a0.z - m) * r * w0.z + b0.z);
    o[3] = (short)f2bf((a0.w - m) * r * w0.w + b0.w);
    o[4] = (short)f2bf((a1.x - m) * r * w1.x + b1.x);
    o[5] = (short)f2bf((a1.y - m) * r * w1.y + b1.y);
    o[6] = (short)f2bf((a1.z - m) * r * w1.z + b1.z);
    o[7] = (short)f2bf((a1.w - m) * r * w1.w + b1.w);
    *(bf16x8*)(out + (size_t)row * HID + k0) = o;
}

// ---------------------------------------------------------------------------
// Transpose fp32 weights to bf16 [n][k] for contiguous GEMM B-fragments.
// ---------------------------------------------------------------------------
__global__ void transpose_kernel(const float* w, const float* rootw,
                                 const float* w1, const float* w2,
                                 u16* WT, u16* rootT, u16* W1T, u16* W2T, int R) {
    int i = blockIdx.x * 256 + threadIdx.x;
    int nW = R * HID * HID;
    if (i < nW) {
        int r = i / (HID * HID); int rem = i % (HID * HID);
        int n = rem / HID, k = rem % HID;
        WT[i] = f2bf(w[r * HID * HID + k * HID + n]);
    } else if (i < nW + HID * HID) {
        int j = i - nW; int n = j / HID, k = j % HID;
        rootT[j] = f2bf(rootw[k * HID + n]);
    } else if (i < nW + HID * HID + FFD * HID) {
        int j = i - nW - HID * HID; int n = j / HID, k = j % HID;
        W1T[j] = f2bf(w1[k * FFD + n]);
    } else if (i < nW + HID * HID + FFD * HID + HID * FFD) {
        int j = i - nW - HID * HID - FFD * HID; int n = j / FFD, k = j % FFD;
        W2T[j] = f2bf(w2[k * HID + n]);
    }
}

// ---------------------------------------------------------------------------
// Fold W_r into attention vectors:  Vsd[n'][k], n' = r*4+h (src) / 32+r*4+h
// (dst).  Vs[r,h,k] = sum_d W[r][k][h*32+d] * att[h*32+d].
// ---------------------------------------------------------------------------
__global__ void vsd_kernel(const float* w, const float* att_src, const float* att_dst,
                           u16* Vsd, int R) {
    int idx = blockIdx.x * 256 + threadIdx.x;
    if (idx >= 64 * HID) return;
    int np = idx >> 7, k = idx & 127;
    int isDst = np >> 5, rh = np & 31, r = rh >> 2, h = rh & 3;
    const float* av = (isDst ? att_dst : att_src) + h * HD;
    const float* wp = w + (size_t)r * HID * HID + (size_t)k * HID + h * HD;
    float s = 0.f;
    #pragma unroll
    for (int d = 0; d < HD; d++) s += wp[d] * av[d];
    Vsd[idx] = f2bf(s);
}

__global__ void ae_kernel(const float* emb, const float* att_edge, float* ae, int R) {
    int i = threadIdx.x;
    if (i >= R * NH) return;
    int r = i >> 2, h = i & 3;
    float s = 0.f;
    #pragma unroll
    for (int d = 0; d < HD; d++)
        s += emb[r * HID + h * HD + d] * att_edge[h * HD + d];
    ae[i] = s;
}

// ---------------------------------------------------------------------------
// Register-resident-A GEMM for K=128, bf16 out.  ytiles=1 now: ONE output
// tile per block, ONE barrier, no serial per-block ytile chain (the compiler
// drains vmcnt(0) at every barrier; 8-ytile blocks serialized 16 drain
// phases at 2-3 blocks/CU -- suspected 1 TB/s floor).  Grid y spans N/64.
// EPI 0: raw bf16    EPI 2: +b1, exact gelu -> bf16
// ---------------------------------------------------------------------------
template <int EPI>
__global__ __launch_bounds__(256)
void gemmy_kernel(const u16* Araw, const u16* BT, u16* Cout, const float* bias,
                  int M, int N, int aOff, int cOff, int ytiles) {
    int w = threadIdx.x >> 6, lane = threadIdx.x & 63;
    int l15 = lane & 15, quad = lane >> 4;
    int m0 = blockIdx.x * 64 + w * 16;
    int rowA = m0 + l15; if (rowA > M - 1) rowA = M - 1;
    const u16* ap = Araw + (size_t)(aOff + rowA) * HID + quad * 8;
    bf16x8 a[4];
    #pragma unroll
    for (int kk = 0; kk < 4; kk++) a[kk] = *(const bf16x8*)(ap + kk * 32);

    __shared__ u16 tile[64][72];
    int rl2 = threadIdx.x >> 3, seg = threadIdx.x & 7;
    int ybase = blockIdx.y * ytiles;
    for (int yi = 0; yi < ytiles; yi++) {
        int n0 = (ybase + yi) * 64;
        f32x4 accr[4] = {};
        #pragma unroll
        for (int kk = 0; kk < 4; kk++) {
            #pragma unroll
            for (int t = 0; t < 4; t++) {
                const u16* bp = BT + (size_t)(n0 + t * 16 + l15) * HID + quad * 8 + kk * 32;
                bf16x8 bfrag = *(const bf16x8*)bp;
                accr[t] = __builtin_amdgcn_mfma_f32_16x16x32_bf16(a[kk], bfrag, accr[t], 0, 0, 0);
            }
        }
        if (yi > 0) __syncthreads();        // prior iter's LDS reads complete
        #pragma unroll
        for (int t = 0; t < 4; t++) {
            int col = n0 + t * 16 + l15;
            #pragma unroll
            for (int j = 0; j < 4; j++) {
                float v = accr[t][j];
                if constexpr (EPI == 2) {
                    v += bias[col];
                    v = 0.5f * v * (1.0f + erff(v * 0.70710678118654752f));
                }
                tile[w * 16 + quad * 4 + j][t * 16 + l15] = f2bf(v);
            }
        }
        __syncthreads();
        #pragma unroll
        for (int h = 0; h < 2; h++) {
            int rl = h * 32 + rl2;
            int row = blockIdx.x * 64 + rl;
            if (row < M) {
                u16* dst = Cout + (size_t)(cOff + row) * N + n0 + seg * 8;
                *(bf16x8*)dst = *(const bf16x8*)&tile[rl][seg * 8];
            }
        }
    }
}

// ---------------------------------------------------------------------------
// General MFMA GEMM, 64x64 block tile, 4 waves, 16x16x32 bf16.
// AM 0: A = fp32 + LN affine -> bf16      AM 2: A = bf16 raw
// EPI 0: raw bf16 (LDS-staged, line-contiguous stores)       [fallback path]
// EPI 1: + acc*invden + bias, elu, + x(fp32) -> FP32 store
// EPI 2: + b1, exact gelu -> bf16 (LDS-staged)               [fallback path]
// EPI 3: + b2 + resid(fp32) -> FP32 store
// EPI 5: split fp32 store: col<32 -> as[row][col], col>=32 -> ad[row][col-32]
// ---------------------------------------------------------------------------
template <int AM, int EPI>
__global__ __launch_bounds__(256)
void gemm_kernel(const void* Araw, const float* mu, const float* rs,
                 const float* lw, const float* lb,
                 const u16* BT, void* Cout, const float* bias,
                 const float* acc, const float* xin, const float* invden,
                 int M, int N, int K, int aOff, int cOff) {
    int w = threadIdx.x >> 6, lane = threadIdx.x & 63;
    int l15 = lane & 15, quad = lane >> 4;
    int m0 = blockIdx.x * 64 + w * 16;
    int n0 = blockIdx.y * 64;
    int rowA = m0 + l15; if (rowA > M - 1) rowA = M - 1;
    int gA = aOff + rowA;
    float muv = 0.f, rsv = 0.f;
    if (AM != 2) { muv = mu[gA]; rsv = rs[gA]; }

    f32x4 accr[4] = {};
    for (int kc = 0; kc < K; kc += 32) {
        bf16x8 a;
        if (AM == 0) {
            const float* ap = (const float*)Araw + (size_t)gA * K + quad * 8 + kc;
            float4 xa0 = *(const float4*)(ap);
            float4 xa1 = *(const float4*)(ap + 4);
            float4 w0 = *(const float4*)(lw + kc + quad * 8);
            float4 w1v = *(const float4*)(lw + kc + quad * 8 + 4);
            float4 b0 = *(const float4*)(lb + kc + quad * 8);
            float4 b1v = *(const float4*)(lb + kc + quad * 8 + 4);
            a[0] = (short)f2bf((xa0.x - muv) * rsv * w0.x + b0.x);
            a[1] = (short)f2bf((xa0.y - muv) * rsv * w0.y + b0.y);
            a[2] = (short)f2bf((xa0.z - muv) * rsv * w0.z + b0.z);
            a[3] = (short)f2bf((xa0.w - muv) * rsv * w0.w + b0.w);
            a[4] = (short)f2bf((xa1.x - muv) * rsv * w1v.x + b1v.x);
            a[5] = (short)f2bf((xa1.y - muv) * rsv * w1v.y + b1v.y);
            a[6] = (short)f2bf((xa1.z - muv) * rsv * w1v.z + b1v.z);
            a[7] = (short)f2bf((xa1.w - muv) * rsv * w1v.w + b1v.w);
        } else {
            const u16* ap = (const u16*)Araw + (size_t)gA * K + quad * 8 + kc;
            a = *(const bf16x8*)ap;
        }
        #pragma unroll
        for (int t = 0; t < 4; t++) {
            const u16* bp = BT + (size_t)(n0 + t * 16 + l15) * K + quad * 8 + kc;
            bf16x8 bfrag = *(const bf16x8*)bp;
            accr[t] = __builtin_amdgcn_mfma_f32_16x16x32_bf16(a, bfrag, accr[t], 0, 0, 0);
        }
    }

    if constexpr (EPI == 0 || EPI == 2) {
        __shared__ u16 tile[64][72];
        #pragma unroll
        for (int t = 0; t < 4; t++) {
            int col = n0 + t * 16 + l15;
            #pragma unroll
            for (int j = 0; j < 4; j++) {
                float v = accr[t][j];
                if (EPI == 2) {
                    v += bias[col];
                    v = 0.5f * v * (1.0f + erff(v * 0.70710678118654752f));
                }
                tile[w * 16 + quad * 4 + j][t * 16 + l15] = f2bf(v);
            }
        }
        __syncthreads();
        int rl2 = threadIdx.x >> 3, seg = threadIdx.x & 7;
        #pragma unroll
        for (int h = 0; h < 2; h++) {
            int rl = h * 32 + rl2;
            int row = blockIdx.x * 64 + rl;
            if (row < M) {
                u16* dst = (u16*)Cout + (size_t)(cOff + row) * N + n0 + seg * 8;
                *(bf16x8*)dst = *(const bf16x8*)&tile[rl][seg * 8];
            }
        }
    } else {
        #pragma unroll
        for (int t = 0; t < 4; t++) {
            int col = n0 + t * 16 + l15;
            #pragma unroll
            for (int j = 0; j < 4; j++) {
                int row = m0 + quad * 4 + j;
                if (row < M) {
                    float v = accr[t][j];
                    int grow = cOff + row;
                    size_t off = (size_t)grow * N + col;
                    if (EPI == 1) {
                        float msg = acc[(size_t)grow * HID + col]
                                  * invden[(size_t)grow * NH + (col >> 5)];
                        float o = v + msg + bias[col];
                        o = o > 0.f ? o : expm1f(o);
                        ((float*)Cout)[off] = xin[off] + o;
                    } else if (EPI == 3) {
                        ((float*)Cout)[off] = v + bias[col] + xin[off];
                    } else if (EPI == 5) {
                        float* tab = (float*)Cout;
                        if (col < 32) tab[(size_t)grow * 32 + col] = v;
                        else tab[(size_t)(M + grow) * 32 + (col - 32)] = v;
                    }
                }
            }
        }
    }
}

// ---------------------------------------------------------------------------
// CSR grouped by (dst, rel): histogram over NN*RR -> scan -> bucketed scatter.
// ---------------------------------------------------------------------------
__global__ void deg_kernel(const int* ei, const int* et, int* deg2, int E, int NN) {
    int e = blockIdx.x * 256 + threadIdx.x;
    if (e >= E) return;
    int s = ei[e], d = ei[E + e], r = et[e];
    if ((unsigned)d < (unsigned)NN && (unsigned)r < (unsigned)RR &&
        (unsigned)s < (unsigned)NN)
        atomicAdd(&deg2[d * RR + r], 1);
}

__global__ void scan1_kernel(const int* in, int* out, int* bsum, int n) {
    __shared__ int buf[SCAN_B];
    int i = blockIdx.x * SCAN_B + threadIdx.x;
    int v = (i < n) ? in[i] : 0;
    buf[threadIdx.x] = v;
    __syncthreads();
    for (int s = 1; s < SCAN_B; s <<= 1) {
        int t = (threadIdx.x >= s) ? buf[threadIdx.x - s] : 0;
        __syncthreads();
        buf[threadIdx.x] += t;
        __syncthreads();
    }
    if (i < n) out[i] = buf[threadIdx.x] - v;
    if (threadIdx.x == SCAN_B - 1) bsum[blockIdx.x] = buf[SCAN_B - 1];
}

__global__ void scan2_kernel(int* bsum, int nb) {
    __shared__ int buf[SCAN_B];
    int v = (threadIdx.x < nb) ? bsum[threadIdx.x] : 0;
    buf[threadIdx.x] = v;
    __syncthreads();
    for (int s = 1; s < SCAN_B; s <<= 1) {
        int t = (threadIdx.x >= s) ? buf[threadIdx.x - s] : 0;
        __syncthreads();
        buf[threadIdx.x] += t;
        __syncthreads();
    }
    if (threadIdx.x < nb) bsum[threadIdx.x] = buf[threadIdx.x] - v;
    if (threadIdx.x == SCAN_B - 1) bsum[nb] = buf[SCAN_B - 1];
}

__global__ void scan3_kernel(int* out, int* curpos, const int* bsum, int n, int nb) {
    int i = blockIdx.x * SCAN_B + threadIdx.x;
    if (i < n) {
        int o = out[i] + bsum[blockIdx.x];
        out[i] = o; curpos[i] = o;
    }
    if (i == 0) out[n] = bsum[nb];
}

// Phase A: append (d | r<<24|s) into the dst-bucket's exact CSR region.
__global__ void fillA_kernel(const int* ei, const int* et, const int* offs2,
                             int* bcnt, u64* tmp, int E, int NN) {
    int e = blockIdx.x * 256 + threadIdx.x;
    if (e >= E) return;
    int s = ei[e], d = ei[E + e], r = et[e];
    if ((unsigned)d >= (unsigned)NN || (unsigned)r >= (unsigned)RR ||
        (unsigned)s >= (unsigned)NN) return;
    int b = d >> NB_SH;
    int base = offs2[(b << NB_SH) * RR];
    int pos = atomicAdd(&bcnt[b * 16], 1);        // 64B-padded counter
    tmp[base + pos] = ((u64)d << 32) | (unsigned)((r << 24) | s);
}

// Phase B: one workgroup per bucket; scatter within the bucket's small region.
__global__ void fillB_kernel(const u64* tmp, const int* offs2,
                             int* curpos2, int* rs_arr, int NN) {
    int b = blockIdx.x;
    int n0 = b << NB_SH;
    int n1 = n0 + (1 << NB_SH); if (n1 > NN) n1 = NN;
    int base = offs2[n0 * RR];
    int end  = offs2[n1 * RR];
    for (int i = base + threadIdx.x; i < end; i += 256) {
        u64 t = tmp[i];
        int d = (int)(t >> 32);
        unsigned v = (unsigned)t;
        int r = v >> 24;
        int pos = atomicAdd(&curpos2[d * RR + r], 1);
        rs_arr[pos] = (int)v;
    }
}

// ---------------------------------------------------------------------------
// Softmax weights: ONE WAVE per dst node (lanes = 16 edge-slots x 4 heads).
// ---------------------------------------------------------------------------
__global__ void wgt_kernel(const int* offs2, const int* rs_arr,
                           const float* asad, const float* ae,
                           float* wgt, float* invden, int NN, int E) {
    int n = blockIdx.x * 4 + (threadIdx.x >> 6);
    if (n >= NN) return;
    int lane = threadIdx.x & 63;
    int el = lane >> 2, h = lane & 3;
    int p0 = offs2[n * RR], p1 = offs2[n * RR + RR];
    const float* ad = asad + (size_t)NN * 32;
    float base[RR];
    #pragma unroll
    for (int r = 0; r < RR; r++)
        base[r] = ad[(size_t)n * 32 + r * 4 + h] + ae[r * 4 + h];
    float mx = -1e30f;
    for (int p = p0 + el; p < p1; p += 16) {
        unsigned v = (unsigned)rs_arr[p];
        int r = v >> 24, s = v & 0xFFFFFF;
        float a = asad[(size_t)s * 32 + r * 4 + h] + base[r];
        a = a > 0.f ? a : 0.2f * a;
        wgt[(size_t)p * NH + h] = a;
        mx = fmaxf(mx, a);
    }
    #pragma unroll
    for (int o = 4; o < 64; o <<= 1) mx = fmaxf(mx, __shfl_xor(mx, o, 64));
    float den = 0.f;
    for (int p = p0 + el; p < p1; p += 16) {
        float ex = __expf(wgt[(size_t)p * NH + h] - mx);
        wgt[(size_t)p * NH + h] = ex;
        den += ex;
    }
    #pragma unroll
    for (int o = 4; o < 64; o <<= 1) den += __shfl_xor(den, o, 64);
    if (el == 0) invden[n * NH + h] = 1.0f / (den + 1e-16f);
}

// ---------------------------------------------------------------------------
// Single-pass message accumulation (xp holds ALL RR relations, ldx=1024).
// ONE WAVE per dst node, 2 channels/lane (u16x2), 4-edge-unrolled gathers
// so 4+ independent loads are in flight per wave (latency hiding).
// ---------------------------------------------------------------------------
__global__ __launch_bounds__(256)
void msg1_kernel(const int* offs2, const int* rs_arr, const float* wgt,
                 const u16* xp, float* acc, int NN) {
    int n = blockIdx.x * 4 + (threadIdx.x >> 6);
    if (n >= NN) return;
    int lane = threadIdx.x & 63;
    int c2 = lane << 1;           // channel pair base
    int h = lane >> 4;            // head = c2>>5
    int p0 = offs2[n * RR], p1 = offs2[n * RR + RR];
    float a0 = 0.f, a1 = 0.f;
    int p = p0;
    for (; p + 4 <= p1; p += 4) {
        unsigned v0 = (unsigned)rs_arr[p + 0];
        unsigned v1 = (unsigned)rs_arr[p + 1];
        unsigned v2 = (unsigned)rs_arr[p + 2];
        unsigned v3 = (unsigned)rs_arr[p + 3];
        unsigned z0 = *(const unsigned*)(xp + (size_t)(v0 & 0xFFFFFFu) * (HID * RR)
                                            + ((v0 >> 24) << 7) + c2);
        unsigned z1 = *(const unsigned*)(xp + (size_t)(v1 & 0xFFFFFFu) * (HID * RR)
                                            + ((v1 >> 24) << 7) + c2);
        unsigned z2 = *(const unsigned*)(xp + (size_t)(v2 & 0xFFFFFFu) * (HID * RR)
                                            + ((v2 >> 24) << 7) + c2);
        unsigned z3 = *(const unsigned*)(xp + (size_t)(v3 & 0xFFFFFFu) * (HID * RR)
                                            + ((v3 >> 24) << 7) + c2);
        float w0 = wgt[(size_t)(p + 0) * NH + h];
        float w1 = wgt[(size_t)(p + 1) * NH + h];
        float w2 = wgt[(size_t)(p + 2) * NH + h];
        float w3 = wgt[(size_t)(p + 3) * NH + h];
        a0 += w0 * bf2f((u16)z0) + w1 * bf2f((u16)z1)
            + w2 * bf2f((u16)z2) + w3 * bf2f((u16)z3);
        a1 += w0 * bf2f((u16)(z0 >> 16)) + w1 * bf2f((u16)(z1 >> 16))
            + w2 * bf2f((u16)(z2 >> 16)) + w3 * bf2f((u16)(z3 >> 16));
    }
    for (; p < p1; p++) {
        unsigned v = (unsigned)rs_arr[p];
        unsigned z = *(const unsigned*)(xp + (size_t)(v & 0xFFFFFFu) * (HID * RR)
                                           + ((v >> 24) << 7) + c2);
        float wv = wgt[(size_t)p * NH + h];
        a0 += wv * bf2f((u16)z);
        a1 += wv * bf2f((u16)(z >> 16));
    }
    float2 o; o.x = a0; o.y = a1;
    *(float2*)(acc + (size_t)n * HID + c2) = o;
}

// ---------------------------------------------------------------------------
// Multi-pass fallback (nrel < RR): one block (128 thr) per dst node, RMW acc.
// ---------------------------------------------------------------------------
__global__ void msg2_kernel(const int* offs2, const int* rs_arr, const float* wgt,
                            const u16* xp, float* acc, int rc, int nrel, int ldx,
                            int NN, int E) {
    int n = blockIdx.x;
    int c = threadIdx.x, h = c >> 5;
    int p0 = offs2[n * RR + rc], p1 = offs2[n * RR + rc + nrel];
    if (p0 >= p1) return;
    float av = acc[(size_t)n * HID + c];
    for (int p = p0; p < p1; p++) {
        unsigned v = (unsigned)rs_arr[p];
        int r = (v >> 24) - rc;
        int s = v & 0xFFFFFF;
        av += wgt[(size_t)p * NH + h] * bf2f(xp[(size_t)s * ldx + r * HID + c]);
    }
    acc[(size_t)n * HID + c] = av;
}

// ---------------------------------------------------------------------------
extern "C" void kernel_launch(void* const* d_in, const int* in_sizes, int n_in,
                              void* d_out, int out_size, void* d_ws, size_t ws_size,
                              hipStream_t stream) {
    const float* x        = (const float*)d_in[0];
    const float* w        = (const float*)d_in[1];
    const float* rootw    = (const float*)d_in[2];
    const float* emb      = (const float*)d_in[3];
    const float* att_src  = (const float*)d_in[4];
    const float* att_dst  = (const float*)d_in[5];
    const float* att_edge = (const float*)d_in[6];
    const float* bias     = (const float*)d_in[7];
    const float* n1w      = (const float*)d_in[8];
    const float* n1b      = (const float*)d_in[9];
    const float* n2w      = (const float*)d_in[10];
    const float* n2b      = (const float*)d_in[11];
    const float* w1       = (const float*)d_in[12];
    const float* b1       = (const float*)d_in[13];
    const float* w2       = (const float*)d_in[14];
    const float* b2       = (const float*)d_in[15];
    const int* ei = (const int*)d_in[16];
    const int* et = (const int*)d_in[17];

    int NN = in_sizes[0] / HID;         // 50000
    int R  = in_sizes[1] / (HID * HID); // 8
    int E  = in_sizes[17];              // 800000
    int NR = NN * RR;
    int NBK = (NN + (1 << NB_SH) - 1) >> NB_SH;   // 782 buckets

    // ---- arena ------------------------------------------------------------
    char* p = (char*)d_ws;
    auto alloc = [&](size_t bytes) -> char* {
        char* q = p; p += (bytes + 255) & ~(size_t)255; return q;
    };
    int* offs2   = (int*)alloc((size_t)(NR + 1) * 4);
    int* rs_arr  = (int*)alloc((size_t)E * 4);
    u16* WTw   = (u16*)alloc((size_t)R * HID * HID * 2);
    u16* rootT = (u16*)alloc((size_t)HID * HID * 2);
    u16* W1T   = (u16*)alloc((size_t)FFD * HID * 2);
    u16* W2T   = (u16*)alloc((size_t)HID * FFD * 2);
    u16* Vsd   = (u16*)alloc((size_t)64 * HID * 2);
    float* ae  = (float*)alloc((size_t)R * NH * 4);
    float* mu1 = (float*)alloc((size_t)NN * 4);
    float* rs1 = (float*)alloc((size_t)NN * 4);
    float* mu2 = (float*)alloc((size_t)NN * 4);
    float* rs2 = (float*)alloc((size_t)NN * 4);
    float* asad   = (float*)alloc((size_t)NN * 64 * 4);   // as|ad tables; later hnorm
    float* invden = (float*)alloc((size_t)NN * NH * 4);
    float* wgt    = (float*)alloc((size_t)E * NH * 4);
    float* acc    = (float*)alloc((size_t)NN * HID * 4);

    // CSR-build scratch aliases the (not-yet-live) wgt buffer (12.8MB).
    int nbScan = (NR + SCAN_B - 1) / SCAN_B;
    int* deg2    = (int*)wgt;
    int* curpos2 = deg2 + NR;
    int* bsum    = curpos2 + NR;
    int* bcnt    = bsum + nbScan + 1;
    u64* tmp     = (u64*)(((size_t)(bcnt + NBK * 16) + 7) & ~(size_t)7);

    // x-projection buffer: as many relations per pass as workspace allows.
    size_t usedFixed = (size_t)(p - (char*)d_ws);
    int nrel = 1;
    for (int t = 8; t > 1; t >>= 1) {
        if (ws_size >= usedFixed + (size_t)NN * HID * t * 2 + 256) { nrel = t; break; }
    }
    u16* xp = (u16*)alloc((size_t)NN * HID * nrel * 2);
    u16* u_ch = xp;                   // alias: FFN intermediate
    u16* hbuf = (u16*)asad;           // alias: NN*64*4B == NN*128*2B exactly
    float* x2 = (float*)d_out;        // x2 lives in d_out until FFN2 overwrites

    size_t used = (size_t)(p - (char*)d_ws);
    if (used > ws_size) {
        zeroout_kernel<<<(out_size + 255) / 256, 256, 0, stream>>>((float*)d_out, out_size);
        return;
    }

    // ---- phase 0: init, stats, weights, CSR -------------------------------
    int single = (nrel == RR) ? 1 : 0;
    int initN = single ? (NR > NBK * 16 ? NR : NBK * 16) : NN * HID;
    init_kernel<<<(initN + 255) / 256, 256, 0, stream>>>(acc, deg2, bcnt, NN, NBK,
                                                         single ? 0 : 1);
    stats_kernel<<<(NN + 3) / 4, 256, 0, stream>>>(x, mu1, rs1, NN);
    int nT = R * HID * HID + HID * HID + FFD * HID + HID * FFD;
    transpose_kernel<<<(nT + 255) / 256, 256, 0, stream>>>(w, rootw, w1, w2,
                                                           WTw, rootT, W1T, W2T, R);
    vsd_kernel<<<(64 * HID + 255) / 256, 256, 0, stream>>>(w, att_src, att_dst, Vsd, R);
    ae_kernel<<<1, 64, 0, stream>>>(emb, att_edge, ae, R);
    deg_kernel<<<(E + 255) / 256, 256, 0, stream>>>(ei, et, deg2, E, NN);
    scan1_kernel<<<nbScan, SCAN_B, 0, stream>>>(deg2, offs2, bsum, NR);
    scan2_kernel<<<1, SCAN_B, 0, stream>>>(bsum, nbScan);
    scan3_kernel<<<nbScan, SCAN_B, 0, stream>>>(offs2, curpos2, bsum, NR, nbScan);
    fillA_kernel<<<(E + 255) / 256, 256, 0, stream>>>(ei, et, offs2, bcnt, tmp, E, NN);
    fillB_kernel<<<NBK, 256, 0, stream>>>(tmp, offs2, curpos2, rs_arr, NN);

    // ---- phase 1: ALL attention dot tables in ONE GEMM (split store) ------
    int gxN = (NN + 63) / 64;
    gemm_kernel<0, 5><<<dim3(gxN, 1), 256, 0, stream>>>(
        x, mu1, rs1, n1w, n1b, Vsd, asad,
        nullptr, nullptr, nullptr, nullptr, NN, 64, HID, 0, 0);

    // ---- phase 2: exact per-edge softmax (unnormalized), wave per node ----
    wgt_kernel<<<(NN + 3) / 4, 256, 0, stream>>>(
        offs2, rs_arr, asad, ae, wgt, invden, NN, E);

    // asad is dead; materialize LN1(x) as bf16 into the same buffer.
    hnorm_kernel<<<(NN * (HID / 8) + 255) / 256, 256, 0, stream>>>(
        x, mu1, rs1, n1w, n1b, hbuf, NN);

    // ---- phase 3: projection + message accumulation -----------------------
    if (single) {
        // ytiles=1: 16 y-blocks, one barrier each (no serial drain chain).
        gemmy_kernel<0><<<dim3(gxN, 16), 256, 0, stream>>>(
            hbuf, WTw, xp, nullptr, NN, HID * RR, 0, 0, 1);
        msg1_kernel<<<(NN + 3) / 4, 256, 0, stream>>>(offs2, rs_arr, wgt, xp, acc, NN);
    } else {
        for (int rc = 0; rc < RR; rc += nrel) {
            gemm_kernel<2, 0><<<dim3(gxN, (HID * nrel) / 64), 256, 0, stream>>>(
                hbuf, nullptr, nullptr, nullptr, nullptr, WTw + (size_t)rc * HID * HID,
                xp, nullptr, nullptr, nullptr, nullptr, NN, HID * nrel, HID, 0, 0);
            msg2_kernel<<<NN, HID, 0, stream>>>(offs2, rs_arr, wgt, xp, acc,
                                                rc, nrel, HID * nrel, NN, E);
        }
    }

    // ---- phase 4: root gemm + msg*invden + bias + elu + residual -> x2 ----
    gemm_kernel<2, 1><<<dim3(gxN, HID / 64), 256, 0, stream>>>(
        hbuf, nullptr, nullptr, nullptr, nullptr, rootT, x2, bias, acc, x, invden,
        NN, HID, HID, 0, 0);

    // ---- phase 5: ln2 stats + hnorm2 + FFN ------------------------------
    stats_kernel<<<(NN + 3) / 4, 256, 0, stream>>>(x2, mu2, rs2, NN);
    hnorm_kernel<<<(NN * (HID / 8) + 255) / 256, 256, 0, stream>>>(
        x2, mu2, rs2, n2w, n2b, hbuf, NN);
    int nchunk = (nrel >= 4) ? 1 : (nrel == 2 ? 2 : 4);
    int NCH = (NN + nchunk - 1) / nchunk;
    for (int j = 0; j < nchunk; j++) {
        int r0 = j * NCH;
        int Mc = NN - r0; if (Mc > NCH) Mc = NCH;
        if (Mc <= 0) continue;
        int gxc = (Mc + 63) / 64;
        // FFN1 (K=128): reg-A GEMM, ytiles=1 (8 y-blocks).
        gemmy_kernel<2><<<dim3(gxc, 8), 256, 0, stream>>>(
            hbuf, W1T, u_ch, b1, Mc, FFD, r0, 0, 1);
        gemm_kernel<2, 3><<<dim3(gxc, HID / 64), 256, 0, stream>>>(
            u_ch, nullptr, nullptr, nullptr, nullptr, W2T, (float*)d_out, b2,
            nullptr, x2, nullptr, Mc, HID, FFD, 0, r0);
    }
}

// Round 15
// 614.371 us; speedup vs baseline: 1.3035x; 1.0073x over previous
//
#include <hip/hip_runtime.h>
#include <hip/hip_bf16.h>
#include <math.h>

#define HID 128
#define NH  4
#define HD  32
#define FFD 512
#define RR  8
#define SCAN_B 1024
#define NB_SH 6              // 64 dst nodes per scatter bucket

typedef __attribute__((ext_vector_type(8))) short bf16x8;
typedef __attribute__((ext_vector_type(4))) float f32x4;
typedef unsigned short u16;
typedef unsigned long long u64;

static __device__ __forceinline__ float bf2f(u16 u) {
    union { unsigned int i; float f; } v; v.i = ((unsigned int)u) << 16; return v.f;
}
static __device__ __forceinline__ u16 f2bf(float f) {
    union { float f; unsigned int i; } v; v.f = f;
    unsigned int x = v.i;
    return (u16)((x + 0x7fffu + ((x >> 16) & 1u)) >> 16);
}

__global__ void zeroout_kernel(float* out, int n) {
    int i = blockIdx.x * 256 + threadIdx.x;
    if (i < n) out[i] = 0.f;
}

// zero deg2 (NN*RR), bcnt (NBK*16); acc only if zacc (multi-pass fallback)
__global__ void init_kernel(float* acc, int* deg2, int* bcnt, int NN, int NBK, int zacc) {
    int i = blockIdx.x * 256 + threadIdx.x;
    if (zacc && i < NN * HID) acc[i] = 0.f;
    if (i < NN * RR) deg2[i] = 0;
    if (i < NBK * 16) bcnt[i] = 0;
}

// ---------------------------------------------------------------------------
// Per-row LayerNorm stats (fp32 input).
// ---------------------------------------------------------------------------
__global__ void stats_kernel(const float* in, float* mu, float* rs, int NN) {
    int row = blockIdx.x * 4 + (threadIdx.x >> 6);
    int lane = threadIdx.x & 63;
    if (row >= NN) return;
    const float* p = in + (size_t)row * HID;
    float v0 = p[lane], v1 = p[lane + 64];
    float s = v0 + v1;
    #pragma unroll
    for (int o = 32; o > 0; o >>= 1) s += __shfl_xor(s, o, 64);
    float m = s * (1.0f / HID);
    float d0 = v0 - m, d1 = v1 - m;
    float q = d0 * d0 + d1 * d1;
    #pragma unroll
    for (int o = 32; o > 0; o >>= 1) q += __shfl_xor(q, o, 64);
    if (lane == 0) { mu[row] = m; rs[row] = rsqrtf(q * (1.0f / HID) + 1e-5f); }
}

// ---------------------------------------------------------------------------
// LN -> bf16 materialization (one thread per 8 elements).
// ---------------------------------------------------------------------------
__global__ void hnorm_kernel(const float* in, const float* mu, const float* rs,
                             const float* lw, const float* lb, u16* out, int NN) {
    int idx = blockIdx.x * 256 + threadIdx.x;
    if (idx >= NN * (HID / 8)) return;
    int row = idx >> 4;            // 16 chunks of 8 per row
    int k0 = (idx & 15) * 8;
    float m = mu[row], r = rs[row];
    const float* p = in + (size_t)row * HID + k0;
    float4 a0 = *(const float4*)p, a1 = *(const float4*)(p + 4);
    float4 w0 = *(const float4*)(lw + k0), w1 = *(const float4*)(lw + k0 + 4);
    float4 b0 = *(const float4*)(lb + k0), b1 = *(const float4*)(lb + k0 + 4);
    bf16x8 o;
    o[0] = (short)f2bf((a0.x - m) * r * w0.x + b0.x);
    o[1] = (short)f2bf((a0.y - m) * r * w0.y + b0.y);
    o[2] = (short)f2bf((a0.z - m) * r * w0.z + b0.z);
    o[3] = (short)f2bf((a0.w - m) * r * w0.w + b0.w);
    o[4] = (short)f2bf((a1.x - m) * r * w1.x + b1.x);
    o[5] = (short)f2bf((a1.y - m) * r * w1.y + b1.y);
    o[6] = (short)f2bf((a1.z - m) * r * w1.z + b1.z);
    o[7] = (short)f2bf((a1.w - m) * r * w1.w + b1.w);
    *(bf16x8*)(out + (size_t)row * HID + k0) = o;
}

// ---------------------------------------------------------------------------
// Transpose fp32 weights to bf16 [n][k] for contiguous GEMM B-fragments.
// ---------------------------------------------------------------------------
__global__ void transpose_kernel(const float* w, const float* rootw,
                                 const float* w1, const float* w2,
                                 u16* WT, u16* rootT, u16* W1T, u16* W2T, int R) {
    int i = blockIdx.x * 256 + threadIdx.x;
    int nW = R * HID * HID;
    if (i < nW) {
        int r = i / (HID * HID); int rem = i % (HID * HID);
        int n = rem / HID, k = rem % HID;
        WT[i] = f2bf(w[r * HID * HID + k * HID + n]);
    } else if (i < nW + HID * HID) {
        int j = i - nW; int n = j / HID, k = j % HID;
        rootT[j] = f2bf(rootw[k * HID + n]);
    } else if (i < nW + HID * HID + FFD * HID) {
        int j = i - nW - HID * HID; int n = j / HID, k = j % HID;
        W1T[j] = f2bf(w1[k * FFD + n]);
    } else if (i < nW + HID * HID + FFD * HID + HID * FFD) {
        int j = i - nW - HID * HID - FFD * HID; int n = j / FFD, k = j % FFD;
        W2T[j] = f2bf(w2[k * HID + n]);
    }
}

// ---------------------------------------------------------------------------
// Fold W_r into attention vectors:  Vsd[n'][k], n' = r*4+h (src) / 32+r*4+h
// (dst).  Vs[r,h,k] = sum_d W[r][k][h*32+d] * att[h*32+d].
// ---------------------------------------------------------------------------
__global__ void vsd_kernel(const float* w, const float* att_src, const float* att_dst,
                           u16* Vsd, int R) {
    int idx = blockIdx.x * 256 + threadIdx.x;
    if (idx >= 64 * HID) return;
    int np = idx >> 7, k = idx & 127;
    int isDst = np >> 5, rh = np & 31, r = rh >> 2, h = rh & 3;
    const float* av = (isDst ? att_dst : att_src) + h * HD;
    const float* wp = w + (size_t)r * HID * HID + (size_t)k * HID + h * HD;
    float s = 0.f;
    #pragma unroll
    for (int d = 0; d < HD; d++) s += wp[d] * av[d];
    Vsd[idx] = f2bf(s);
}

__global__ void ae_kernel(const float* emb, const float* att_edge, float* ae, int R) {
    int i = threadIdx.x;
    if (i >= R * NH) return;
    int r = i >> 2, h = i & 3;
    float s = 0.f;
    #pragma unroll
    for (int d = 0; d < HD; d++)
        s += emb[r * HID + h * HD + d] * att_edge[h * HD + d];
    ae[i] = s;
}

// ---------------------------------------------------------------------------
// Register-resident-A GEMM for K=128, bf16 out.  A frags loaded ONCE, y-loop
// streams B.  TILED=1: output stored as 64x64 subtiles (8KB contiguous each)
// at base (bx*(N/64)+yt)*4096 elems -- each wave's store covers 1KB
// CONTIGUOUS (8 rows x 128B) and a block writes 64KB sequentially.  Theory:
// HBM write drain caps ~1 TB/s for fragmented per-wave streams (all prior
// layouts); dense per-wave streams (like the D2D copy bench) unlock >2 TB/s.
// EPI 0: raw bf16    EPI 2: +b1, exact gelu -> bf16
// ---------------------------------------------------------------------------
template <int EPI, int TILED>
__global__ __launch_bounds__(256)
void gemmy_kernel(const u16* Araw, const u16* BT, u16* Cout, const float* bias,
                  int M, int N, int aOff, int cOff, int ytiles) {
    int w = threadIdx.x >> 6, lane = threadIdx.x & 63;
    int l15 = lane & 15, quad = lane >> 4;
    int m0 = blockIdx.x * 64 + w * 16;
    int rowA = m0 + l15; if (rowA > M - 1) rowA = M - 1;
    const u16* ap = Araw + (size_t)(aOff + rowA) * HID + quad * 8;
    bf16x8 a[4];
    #pragma unroll
    for (int kk = 0; kk < 4; kk++) a[kk] = *(const bf16x8*)(ap + kk * 32);

    __shared__ u16 tile[64][72];
    int rl2 = threadIdx.x >> 3, seg = threadIdx.x & 7;
    int ybase = blockIdx.y * ytiles;
    int nsub = N >> 6;
    for (int yi = 0; yi < ytiles; yi++) {
        int n0 = (ybase + yi) * 64;
        f32x4 accr[4] = {};
        #pragma unroll
        for (int kk = 0; kk < 4; kk++) {
            #pragma unroll
            for (int t = 0; t < 4; t++) {
                const u16* bp = BT + (size_t)(n0 + t * 16 + l15) * HID + quad * 8 + kk * 32;
                bf16x8 bfrag = *(const bf16x8*)bp;
                accr[t] = __builtin_amdgcn_mfma_f32_16x16x32_bf16(a[kk], bfrag, accr[t], 0, 0, 0);
            }
        }
        if (yi > 0) __syncthreads();        // prior iter's LDS reads complete
        #pragma unroll
        for (int t = 0; t < 4; t++) {
            int col = n0 + t * 16 + l15;
            #pragma unroll
            for (int j = 0; j < 4; j++) {
                float v = accr[t][j];
                if constexpr (EPI == 2) {
                    v += bias[col];
                    v = 0.5f * v * (1.0f + erff(v * 0.70710678118654752f));
                }
                tile[w * 16 + quad * 4 + j][t * 16 + l15] = f2bf(v);
            }
        }
        __syncthreads();
        if constexpr (TILED) {
            u16* tb = Cout + (((size_t)blockIdx.x * nsub + (ybase + yi)) << 12);
            #pragma unroll
            for (int h = 0; h < 2; h++) {
                int rl = h * 32 + rl2;
                int row = blockIdx.x * 64 + rl;
                if (row < M) {
                    // 64-col subtile: cols [0,64) of this yi; LDS holds them
                    // at tile[rl][0..64) (t*16+l15 spans 0..63 for this yi).
                    *(bf16x8*)(tb + (rl << 6) + seg * 8) =
                        *(const bf16x8*)&tile[rl][seg * 8];
                }
            }
        } else {
            #pragma unroll
            for (int h = 0; h < 2; h++) {
                int rl = h * 32 + rl2;
                int row = blockIdx.x * 64 + rl;
                if (row < M) {
                    u16* dst = Cout + (size_t)(cOff + row) * N + n0 + seg * 8;
                    *(bf16x8*)dst = *(const bf16x8*)&tile[rl][seg * 8];
                }
            }
        }
    }
}

// ---------------------------------------------------------------------------
// General MFMA GEMM, 64x64 block tile, 4 waves, 16x16x32 bf16.
// AM 0: A = fp32 + LN affine -> bf16      AM 2: A = bf16 raw
// EPI 0: raw bf16 (LDS-staged)   EPI 1: + acc*invden + bias, elu, + x -> FP32
// EPI 2: + b1, gelu -> bf16      EPI 3: + b2 + resid -> FP32
// EPI 5: split fp32 store (as/ad tables)
// ---------------------------------------------------------------------------
template <int AM, int EPI>
__global__ __launch_bounds__(256)
void gemm_kernel(const void* Araw, const float* mu, const float* rs,
                 const float* lw, const float* lb,
                 const u16* BT, void* Cout, const float* bias,
                 const float* acc, const float* xin, const float* invden,
                 int M, int N, int K, int aOff, int cOff) {
    int w = threadIdx.x >> 6, lane = threadIdx.x & 63;
    int l15 = lane & 15, quad = lane >> 4;
    int m0 = blockIdx.x * 64 + w * 16;
    int n0 = blockIdx.y * 64;
    int rowA = m0 + l15; if (rowA > M - 1) rowA = M - 1;
    int gA = aOff + rowA;
    float muv = 0.f, rsv = 0.f;
    if (AM != 2) { muv = mu[gA]; rsv = rs[gA]; }

    f32x4 accr[4] = {};
    for (int kc = 0; kc < K; kc += 32) {
        bf16x8 a;
        if (AM == 0) {
            const float* ap = (const float*)Araw + (size_t)gA * K + quad * 8 + kc;
            float4 xa0 = *(const float4*)(ap);
            float4 xa1 = *(const float4*)(ap + 4);
            float4 w0 = *(const float4*)(lw + kc + quad * 8);
            float4 w1v = *(const float4*)(lw + kc + quad * 8 + 4);
            float4 b0 = *(const float4*)(lb + kc + quad * 8);
            float4 b1v = *(const float4*)(lb + kc + quad * 8 + 4);
            a[0] = (short)f2bf((xa0.x - muv) * rsv * w0.x + b0.x);
            a[1] = (short)f2bf((xa0.y - muv) * rsv * w0.y + b0.y);
            a[2] = (short)f2bf((xa0.z - muv) * rsv * w0.z + b0.z);
            a[3] = (short)f2bf((xa0.w - muv) * rsv * w0.w + b0.w);
            a[4] = (short)f2bf((xa1.x - muv) * rsv * w1v.x + b1v.x);
            a[5] = (short)f2bf((xa1.y - muv) * rsv * w1v.y + b1v.y);
            a[6] = (short)f2bf((xa1.z - muv) * rsv * w1v.z + b1v.z);
            a[7] = (short)f2bf((xa1.w - muv) * rsv * w1v.w + b1v.w);
        } else {
            const u16* ap = (const u16*)Araw + (size_t)gA * K + quad * 8 + kc;
            a = *(const bf16x8*)ap;
        }
        #pragma unroll
        for (int t = 0; t < 4; t++) {
            const u16* bp = BT + (size_t)(n0 + t * 16 + l15) * K + quad * 8 + kc;
            bf16x8 bfrag = *(const bf16x8*)bp;
            accr[t] = __builtin_amdgcn_mfma_f32_16x16x32_bf16(a, bfrag, accr[t], 0, 0, 0);
        }
    }

    if constexpr (EPI == 0 || EPI == 2) {
        __shared__ u16 tile[64][72];
        #pragma unroll
        for (int t = 0; t < 4; t++) {
            int col = n0 + t * 16 + l15;
            #pragma unroll
            for (int j = 0; j < 4; j++) {
                float v = accr[t][j];
                if (EPI == 2) {
                    v += bias[col];
                    v = 0.5f * v * (1.0f + erff(v * 0.70710678118654752f));
                }
                tile[w * 16 + quad * 4 + j][t * 16 + l15] = f2bf(v);
            }
        }
        __syncthreads();
        int rl2 = threadIdx.x >> 3, seg = threadIdx.x & 7;
        #pragma unroll
        for (int h = 0; h < 2; h++) {
            int rl = h * 32 + rl2;
            int row = blockIdx.x * 64 + rl;
            if (row < M) {
                u16* dst = (u16*)Cout + (size_t)(cOff + row) * N + n0 + seg * 8;
                *(bf16x8*)dst = *(const bf16x8*)&tile[rl][seg * 8];
            }
        }
    } else {
        #pragma unroll
        for (int t = 0; t < 4; t++) {
            int col = n0 + t * 16 + l15;
            #pragma unroll
            for (int j = 0; j < 4; j++) {
                int row = m0 + quad * 4 + j;
                if (row < M) {
                    float v = accr[t][j];
                    int grow = cOff + row;
                    size_t off = (size_t)grow * N + col;
                    if (EPI == 1) {
                        float msg = acc[(size_t)grow * HID + col]
                                  * invden[(size_t)grow * NH + (col >> 5)];
                        float o = v + msg + bias[col];
                        o = o > 0.f ? o : expm1f(o);
                        ((float*)Cout)[off] = xin[off] + o;
                    } else if (EPI == 3) {
                        ((float*)Cout)[off] = v + bias[col] + xin[off];
                    } else if (EPI == 5) {
                        float* tab = (float*)Cout;
                        if (col < 32) tab[(size_t)grow * 32 + col] = v;
                        else tab[(size_t)(M + grow) * 32 + (col - 32)] = v;
                    }
                }
            }
        }
    }
}

// ---------------------------------------------------------------------------
// CSR grouped by (dst, rel): histogram over NN*RR -> scan -> bucketed scatter.
// ---------------------------------------------------------------------------
__global__ void deg_kernel(const int* ei, const int* et, int* deg2, int E, int NN) {
    int e = blockIdx.x * 256 + threadIdx.x;
    if (e >= E) return;
    int s = ei[e], d = ei[E + e], r = et[e];
    if ((unsigned)d < (unsigned)NN && (unsigned)r < (unsigned)RR &&
        (unsigned)s < (unsigned)NN)
        atomicAdd(&deg2[d * RR + r], 1);
}

__global__ void scan1_kernel(const int* in, int* out, int* bsum, int n) {
    __shared__ int buf[SCAN_B];
    int i = blockIdx.x * SCAN_B + threadIdx.x;
    int v = (i < n) ? in[i] : 0;
    buf[threadIdx.x] = v;
    __syncthreads();
    for (int s = 1; s < SCAN_B; s <<= 1) {
        int t = (threadIdx.x >= s) ? buf[threadIdx.x - s] : 0;
        __syncthreads();
        buf[threadIdx.x] += t;
        __syncthreads();
    }
    if (i < n) out[i] = buf[threadIdx.x] - v;
    if (threadIdx.x == SCAN_B - 1) bsum[blockIdx.x] = buf[SCAN_B - 1];
}

__global__ void scan2_kernel(int* bsum, int nb) {
    __shared__ int buf[SCAN_B];
    int v = (threadIdx.x < nb) ? bsum[threadIdx.x] : 0;
    buf[threadIdx.x] = v;
    __syncthreads();
    for (int s = 1; s < SCAN_B; s <<= 1) {
        int t = (threadIdx.x >= s) ? buf[threadIdx.x - s] : 0;
        __syncthreads();
        buf[threadIdx.x] += t;
        __syncthreads();
    }
    if (threadIdx.x < nb) bsum[threadIdx.x] = buf[threadIdx.x] - v;
    if (threadIdx.x == SCAN_B - 1) bsum[nb] = buf[SCAN_B - 1];
}

__global__ void scan3_kernel(int* out, int* curpos, const int* bsum, int n, int nb) {
    int i = blockIdx.x * SCAN_B + threadIdx.x;
    if (i < n) {
        int o = out[i] + bsum[blockIdx.x];
        out[i] = o; curpos[i] = o;
    }
    if (i == 0) out[n] = bsum[nb];
}

// Phase A: append (d | r<<24|s) into the dst-bucket's exact CSR region.
__global__ void fillA_kernel(const int* ei, const int* et, const int* offs2,
                             int* bcnt, u64* tmp, int E, int NN) {
    int e = blockIdx.x * 256 + threadIdx.x;
    if (e >= E) return;
    int s = ei[e], d = ei[E + e], r = et[e];
    if ((unsigned)d >= (unsigned)NN || (unsigned)r >= (unsigned)RR ||
        (unsigned)s >= (unsigned)NN) return;
    int b = d >> NB_SH;
    int base = offs2[(b << NB_SH) * RR];
    int pos = atomicAdd(&bcnt[b * 16], 1);        // 64B-padded counter
    tmp[base + pos] = ((u64)d << 32) | (unsigned)((r << 24) | s);
}

// Phase B: one workgroup per bucket; scatter within the bucket's small region.
__global__ void fillB_kernel(const u64* tmp, const int* offs2,
                             int* curpos2, int* rs_arr, int NN) {
    int b = blockIdx.x;
    int n0 = b << NB_SH;
    int n1 = n0 + (1 << NB_SH); if (n1 > NN) n1 = NN;
    int base = offs2[n0 * RR];
    int end  = offs2[n1 * RR];
    for (int i = base + threadIdx.x; i < end; i += 256) {
        u64 t = tmp[i];
        int d = (int)(t >> 32);
        unsigned v = (unsigned)t;
        int r = v >> 24;
        int pos = atomicAdd(&curpos2[d * RR + r], 1);
        rs_arr[pos] = (int)v;
    }
}

// ---------------------------------------------------------------------------
// Softmax weights: ONE WAVE per dst node (lanes = 16 edge-slots x 4 heads).
// ---------------------------------------------------------------------------
__global__ void wgt_kernel(const int* offs2, const int* rs_arr,
                           const float* asad, const float* ae,
                           float* wgt, float* invden, int NN, int E) {
    int n = blockIdx.x * 4 + (threadIdx.x >> 6);
    if (n >= NN) return;
    int lane = threadIdx.x & 63;
    int el = lane >> 2, h = lane & 3;
    int p0 = offs2[n * RR], p1 = offs2[n * RR + RR];
    const float* ad = asad + (size_t)NN * 32;
    float base[RR];
    #pragma unroll
    for (int r = 0; r < RR; r++)
        base[r] = ad[(size_t)n * 32 + r * 4 + h] + ae[r * 4 + h];
    float mx = -1e30f;
    for (int p = p0 + el; p < p1; p += 16) {
        unsigned v = (unsigned)rs_arr[p];
        int r = v >> 24, s = v & 0xFFFFFF;
        float a = asad[(size_t)s * 32 + r * 4 + h] + base[r];
        a = a > 0.f ? a : 0.2f * a;
        wgt[(size_t)p * NH + h] = a;
        mx = fmaxf(mx, a);
    }
    #pragma unroll
    for (int o = 4; o < 64; o <<= 1) mx = fmaxf(mx, __shfl_xor(mx, o, 64));
    float den = 0.f;
    for (int p = p0 + el; p < p1; p += 16) {
        float ex = __expf(wgt[(size_t)p * NH + h] - mx);
        wgt[(size_t)p * NH + h] = ex;
        den += ex;
    }
    #pragma unroll
    for (int o = 4; o < 64; o <<= 1) den += __shfl_xor(den, o, 64);
    if (el == 0) invden[n * NH + h] = 1.0f / (den + 1e-16f);
}

// ---------------------------------------------------------------------------
// Single-pass message accumulation over TILED xp: subtile (s>>6, r*2+half)
// of 64x64 elems at ((s>>6)*16 + r*2 + half)*4096; lane reads 4B at
// (s&63)*64 + 2*(lane&31).  ONE WAVE per dst node, 4-edge-unrolled gathers.
// ---------------------------------------------------------------------------
__global__ __launch_bounds__(256)
void msg1_kernel(const int* offs2, const int* rs_arr, const float* wgt,
                 const u16* xp, float* acc, int NN) {
    int n = blockIdx.x * 4 + (threadIdx.x >> 6);
    if (n >= NN) return;
    int lane = threadIdx.x & 63;
    int half = lane >> 5;          // which 64-col subtile of the 128-col row
    int co = (lane & 31) << 1;     // element pair within subtile row
    int h = lane >> 4;             // head = (2*lane)>>5
    int p0 = offs2[n * RR], p1 = offs2[n * RR + RR];
    float a0 = 0.f, a1 = 0.f;
    int p = p0;
    for (; p + 4 <= p1; p += 4) {
        unsigned v0 = (unsigned)rs_arr[p + 0];
        unsigned v1 = (unsigned)rs_arr[p + 1];
        unsigned v2 = (unsigned)rs_arr[p + 2];
        unsigned v3 = (unsigned)rs_arr[p + 3];
        unsigned s0 = v0 & 0xFFFFFFu, s1 = v1 & 0xFFFFFFu;
        unsigned s2 = v2 & 0xFFFFFFu, s3 = v3 & 0xFFFFFFu;
        unsigned z0 = *(const unsigned*)(xp
            + (((size_t)(s0 >> 6) * 16 + ((v0 >> 24) << 1) + half) << 12)
            + ((s0 & 63) << 6) + co);
        unsigned z1 = *(const unsigned*)(xp
            + (((size_t)(s1 >> 6) * 16 + ((v1 >> 24) << 1) + half) << 12)
            + ((s1 & 63) << 6) + co);
        unsigned z2 = *(const unsigned*)(xp
            + (((size_t)(s2 >> 6) * 16 + ((v2 >> 24) << 1) + half) << 12)
            + ((s2 & 63) << 6) + co);
        unsigned z3 = *(const unsigned*)(xp
            + (((size_t)(s3 >> 6) * 16 + ((v3 >> 24) << 1) + half) << 12)
            + ((s3 & 63) << 6) + co);
        float w0 = wgt[(size_t)(p + 0) * NH + h];
        float w1 = wgt[(size_t)(p + 1) * NH + h];
        float w2 = wgt[(size_t)(p + 2) * NH + h];
        float w3 = wgt[(size_t)(p + 3) * NH + h];
        a0 += w0 * bf2f((u16)z0) + w1 * bf2f((u16)z1)
            + w2 * bf2f((u16)z2) + w3 * bf2f((u16)z3);
        a1 += w0 * bf2f((u16)(z0 >> 16)) + w1 * bf2f((u16)(z1 >> 16))
            + w2 * bf2f((u16)(z2 >> 16)) + w3 * bf2f((u16)(z3 >> 16));
    }
    for (; p < p1; p++) {
        unsigned v = (unsigned)rs_arr[p];
        unsigned s = v & 0xFFFFFFu;
        unsigned z = *(const unsigned*)(xp
            + (((size_t)(s >> 6) * 16 + ((v >> 24) << 1) + half) << 12)
            + ((s & 63) << 6) + co);
        float wv = wgt[(size_t)p * NH + h];
        a0 += wv * bf2f((u16)z);
        a1 += wv * bf2f((u16)(z >> 16));
    }
    float2 o; o.x = a0; o.y = a1;
    *(float2*)(acc + (size_t)n * HID + (lane << 1)) = o;
}

// ---------------------------------------------------------------------------
// Multi-pass fallback (nrel < RR): one block (128 thr) per dst node, RMW acc.
// ---------------------------------------------------------------------------
__global__ void msg2_kernel(const int* offs2, const int* rs_arr, const float* wgt,
                            const u16* xp, float* acc, int rc, int nrel, int ldx,
                            int NN, int E) {
    int n = blockIdx.x;
    int c = threadIdx.x, h = c >> 5;
    int p0 = offs2[n * RR + rc], p1 = offs2[n * RR + rc + nrel];
    if (p0 >= p1) return;
    float av = acc[(size_t)n * HID + c];
    for (int p = p0; p < p1; p++) {
        unsigned v = (unsigned)rs_arr[p];
        int r = (v >> 24) - rc;
        int s = v & 0xFFFFFF;
        av += wgt[(size_t)p * NH + h] * bf2f(xp[(size_t)s * ldx + r * HID + c]);
    }
    acc[(size_t)n * HID + c] = av;
}

// ---------------------------------------------------------------------------
extern "C" void kernel_launch(void* const* d_in, const int* in_sizes, int n_in,
                              void* d_out, int out_size, void* d_ws, size_t ws_size,
                              hipStream_t stream) {
    const float* x        = (const float*)d_in[0];
    const float* w        = (const float*)d_in[1];
    const float* rootw    = (const float*)d_in[2];
    const float* emb      = (const float*)d_in[3];
    const float* att_src  = (const float*)d_in[4];
    const float* att_dst  = (const float*)d_in[5];
    const float* att_edge = (const float*)d_in[6];
    const float* bias     = (const float*)d_in[7];
    const float* n1w      = (const float*)d_in[8];
    const float* n1b      = (const float*)d_in[9];
    const float* n2w      = (const float*)d_in[10];
    const float* n2b      = (const float*)d_in[11];
    const float* w1       = (const float*)d_in[12];
    const float* b1       = (const float*)d_in[13];
    const float* w2       = (const float*)d_in[14];
    const float* b2       = (const float*)d_in[15];
    const int* ei = (const int*)d_in[16];
    const int* et = (const int*)d_in[17];

    int NN = in_sizes[0] / HID;         // 50000
    int R  = in_sizes[1] / (HID * HID); // 8
    int E  = in_sizes[17];              // 800000
    int NR = NN * RR;
    int NBK = (NN + (1 << NB_SH) - 1) >> NB_SH;   // 782 buckets
    int gxN = (NN + 63) / 64;
    int Mpad = gxN * 64;                // tiled xp row capacity

    // ---- arena ------------------------------------------------------------
    char* p = (char*)d_ws;
    auto alloc = [&](size_t bytes) -> char* {
        char* q = p; p += (bytes + 255) & ~(size_t)255; return q;
    };
    int* offs2   = (int*)alloc((size_t)(NR + 1) * 4);
    int* rs_arr  = (int*)alloc((size_t)E * 4);
    u16* WTw   = (u16*)alloc((size_t)R * HID * HID * 2);
    u16* rootT = (u16*)alloc((size_t)HID * HID * 2);
    u16* W1T   = (u16*)alloc((size_t)FFD * HID * 2);
    u16* W2T   = (u16*)alloc((size_t)HID * FFD * 2);
    u16* Vsd   = (u16*)alloc((size_t)64 * HID * 2);
    float* ae  = (float*)alloc((size_t)R * NH * 4);
    float* mu1 = (float*)alloc((size_t)NN * 4);
    float* rs1 = (float*)alloc((size_t)NN * 4);
    float* mu2 = (float*)alloc((size_t)NN * 4);
    float* rs2 = (float*)alloc((size_t)NN * 4);
    float* asad   = (float*)alloc((size_t)NN * 64 * 4);   // as|ad tables; later hnorm
    float* invden = (float*)alloc((size_t)NN * NH * 4);
    float* wgt    = (float*)alloc((size_t)E * NH * 4);
    float* acc    = (float*)alloc((size_t)NN * HID * 4);

    // CSR-build scratch aliases the (not-yet-live) wgt buffer (12.8MB).
    int nbScan = (NR + SCAN_B - 1) / SCAN_B;
    int* deg2    = (int*)wgt;
    int* curpos2 = deg2 + NR;
    int* bsum    = curpos2 + NR;
    int* bcnt    = bsum + nbScan + 1;
    u64* tmp     = (u64*)(((size_t)(bcnt + NBK * 16) + 7) & ~(size_t)7);

    // x-projection buffer (tiled when nrel==8: Mpad rows).
    size_t usedFixed = (size_t)(p - (char*)d_ws);
    int nrel = 1;
    for (int t = 8; t > 1; t >>= 1) {
        size_t rows = (t == 8) ? (size_t)Mpad : (size_t)NN;
        if (ws_size >= usedFixed + rows * HID * t * 2 + 256) { nrel = t; break; }
    }
    size_t xrows = (nrel == 8) ? (size_t)Mpad : (size_t)NN;
    u16* xp = (u16*)alloc(xrows * HID * nrel * 2);
    u16* u_ch = xp;                   // alias: FFN intermediate
    u16* hbuf = (u16*)asad;           // alias: NN*64*4B == NN*128*2B exactly
    float* x2 = (float*)d_out;        // x2 lives in d_out until FFN2 overwrites

    size_t used = (size_t)(p - (char*)d_ws);
    if (used > ws_size) {
        zeroout_kernel<<<(out_size + 255) / 256, 256, 0, stream>>>((float*)d_out, out_size);
        return;
    }

    // ---- phase 0: init, stats, weights, CSR -------------------------------
    int single = (nrel == RR) ? 1 : 0;
    int initN = single ? (NR > NBK * 16 ? NR : NBK * 16) : NN * HID;
    init_kernel<<<(initN + 255) / 256, 256, 0, stream>>>(acc, deg2, bcnt, NN, NBK,
                                                         single ? 0 : 1);
    stats_kernel<<<(NN + 3) / 4, 256, 0, stream>>>(x, mu1, rs1, NN);
    int nT = R * HID * HID + HID * HID + FFD * HID + HID * FFD;
    transpose_kernel<<<(nT + 255) / 256, 256, 0, stream>>>(w, rootw, w1, w2,
                                                           WTw, rootT, W1T, W2T, R);
    vsd_kernel<<<(64 * HID + 255) / 256, 256, 0, stream>>>(w, att_src, att_dst, Vsd, R);
    ae_kernel<<<1, 64, 0, stream>>>(emb, att_edge, ae, R);
    deg_kernel<<<(E + 255) / 256, 256, 0, stream>>>(ei, et, deg2, E, NN);
    scan1_kernel<<<nbScan, SCAN_B, 0, stream>>>(deg2, offs2, bsum, NR);
    scan2_kernel<<<1, SCAN_B, 0, stream>>>(bsum, nbScan);
    scan3_kernel<<<nbScan, SCAN_B, 0, stream>>>(offs2, curpos2, bsum, NR, nbScan);
    fillA_kernel<<<(E + 255) / 256, 256, 0, stream>>>(ei, et, offs2, bcnt, tmp, E, NN);
    fillB_kernel<<<NBK, 256, 0, stream>>>(tmp, offs2, curpos2, rs_arr, NN);

    // ---- phase 1: ALL attention dot tables in ONE GEMM (split store) ------
    gemm_kernel<0, 5><<<dim3(gxN, 1), 256, 0, stream>>>(
        x, mu1, rs1, n1w, n1b, Vsd, asad,
        nullptr, nullptr, nullptr, nullptr, NN, 64, HID, 0, 0);

    // ---- phase 2: exact per-edge softmax (unnormalized), wave per node ----
    wgt_kernel<<<(NN + 3) / 4, 256, 0, stream>>>(
        offs2, rs_arr, asad, ae, wgt, invden, NN, E);

    // asad is dead; materialize LN1(x) as bf16 into the same buffer.
    hnorm_kernel<<<(NN * (HID / 8) + 255) / 256, 256, 0, stream>>>(
        x, mu1, rs1, n1w, n1b, hbuf, NN);

    // ---- phase 3: projection + message accumulation -----------------------
    if (single) {
        gemmy_kernel<0, 1><<<dim3(gxN, 2), 256, 0, stream>>>(
            hbuf, WTw, xp, nullptr, NN, HID * RR, 0, 0, 8);
        msg1_kernel<<<(NN + 3) / 4, 256, 0, stream>>>(offs2, rs_arr, wgt, xp, acc, NN);
    } else {
        for (int rc = 0; rc < RR; rc += nrel) {
            gemm_kernel<2, 0><<<dim3(gxN, (HID * nrel) / 64), 256, 0, stream>>>(
                hbuf, nullptr, nullptr, nullptr, nullptr, WTw + (size_t)rc * HID * HID,
                xp, nullptr, nullptr, nullptr, nullptr, NN, HID * nrel, HID, 0, 0);
            msg2_kernel<<<NN, HID, 0, stream>>>(offs2, rs_arr, wgt, xp, acc,
                                                rc, nrel, HID * nrel, NN, E);
        }
    }

    // ---- phase 4: root gemm + msg*invden + bias + elu + residual -> x2 ----
    gemm_kernel<2, 1><<<dim3(gxN, HID / 64), 256, 0, stream>>>(
        hbuf, nullptr, nullptr, nullptr, nullptr, rootT, x2, bias, acc, x, invden,
        NN, HID, HID, 0, 0);

    // ---- phase 5: ln2 stats + hnorm2 + FFN ------------------------------
    stats_kernel<<<(NN + 3) / 4, 256, 0, stream>>>(x2, mu2, rs2, NN);
    hnorm_kernel<<<(NN * (HID / 8) + 255) / 256, 256, 0, stream>>>(
        x2, mu2, rs2, n2w, n2b, hbuf, NN);
    int nchunk = (nrel >= 4) ? 1 : (nrel == 2 ? 2 : 4);
    int NCH = (NN + nchunk - 1) / nchunk;
    for (int j = 0; j < nchunk; j++) {
        int r0 = j * NCH;
        int Mc = NN - r0; if (Mc > NCH) Mc = NCH;
        if (Mc <= 0) continue;
        int gxc = (Mc + 63) / 64;
        // FFN1 (K=128): reg-A GEMM, untiled (R9 config).
        gemmy_kernel<2, 0><<<dim3(gxc, 2), 256, 0, stream>>>(
            hbuf, W1T, u_ch, b1, Mc, FFD, r0, 0, 4);
        gemm_kernel<2, 3><<<dim3(gxc, HID / 64), 256, 0, stream>>>(
            u_ch, nullptr, nullptr, nullptr, nullptr, W2T, (float*)d_out, b2,
            nullptr, x2, nullptr, Mc, HID, FFD, 0, r0);
    }
}

// Round 16
// 588.059 us; speedup vs baseline: 1.3618x; 1.0447x over previous
//
#include <hip/hip_runtime.h>
#include <hip/hip_bf16.h>
#include <math.h>

#define HID 128
#define NH  4
#define HD  32
#define FFD 512
#define RR  8
#define SCAN_B 1024
#define NB_SH 6              // 64 dst nodes per scatter bucket

typedef __attribute__((ext_vector_type(8))) short bf16x8;
typedef __attribute__((ext_vector_type(4))) float f32x4;
typedef unsigned short u16;
typedef unsigned long long u64;

static __device__ __forceinline__ float bf2f(u16 u) {
    union { unsigned int i; float f; } v; v.i = ((unsigned int)u) << 16; return v.f;
}
static __device__ __forceinline__ u16 f2bf(float f) {
    union { float f; unsigned int i; } v; v.f = f;
    unsigned int x = v.i;
    return (u16)((x + 0x7fffu + ((x >> 16) & 1u)) >> 16);
}

__global__ void zeroout_kernel(float* out, int n) {
    int i = blockIdx.x * 256 + threadIdx.x;
    if (i < n) out[i] = 0.f;
}

// zero deg2 (NN*RR), bcnt (NBK*16); acc only if zacc (multi-pass fallback)
__global__ void init_kernel(float* acc, int* deg2, int* bcnt, int NN, int NBK, int zacc) {
    int i = blockIdx.x * 256 + threadIdx.x;
    if (zacc && i < NN * HID) acc[i] = 0.f;
    if (i < NN * RR) deg2[i] = 0;
    if (i < NBK * 16) bcnt[i] = 0;
}

// ---------------------------------------------------------------------------
// Per-row LayerNorm stats (fp32 input).
// ---------------------------------------------------------------------------
__global__ void stats_kernel(const float* in, float* mu, float* rs, int NN) {
    int row = blockIdx.x * 4 + (threadIdx.x >> 6);
    int lane = threadIdx.x & 63;
    if (row >= NN) return;
    const float* p = in + (size_t)row * HID;
    float v0 = p[lane], v1 = p[lane + 64];
    float s = v0 + v1;
    #pragma unroll
    for (int o = 32; o > 0; o >>= 1) s += __shfl_xor(s, o, 64);
    float m = s * (1.0f / HID);
    float d0 = v0 - m, d1 = v1 - m;
    float q = d0 * d0 + d1 * d1;
    #pragma unroll
    for (int o = 32; o > 0; o >>= 1) q += __shfl_xor(q, o, 64);
    if (lane == 0) { mu[row] = m; rs[row] = rsqrtf(q * (1.0f / HID) + 1e-5f); }
}

// ---------------------------------------------------------------------------
// LN -> bf16 body (shared by hnorm_kernel and fused1).
// ---------------------------------------------------------------------------
static __device__ __forceinline__
void hnorm_body(int idx, const float* in, const float* mu, const float* rs,
                const float* lw, const float* lb, u16* out, int NN) {
    if (idx >= NN * (HID / 8)) return;
    int row = idx >> 4;
    int k0 = (idx & 15) * 8;
    float m = mu[row], r = rs[row];
    const float* p = in + (size_t)row * HID + k0;
    float4 a0 = *(const float4*)p, a1 = *(const float4*)(p + 4);
    float4 w0 = *(const float4*)(lw + k0), w1 = *(const float4*)(lw + k0 + 4);
    float4 b0 = *(const float4*)(lb + k0), b1 = *(const float4*)(lb + k0 + 4);
    bf16x8 o;
    o[0] = (short)f2bf((a0.x - m) * r * w0.x + b0.x);
    o[1] = (short)f2bf((a0.y - m) * r * w0.y + b0.y);
    o[2] = (short)f2bf((a0.z - m) * r * w0.z + b0.z);
    o[3] = (short)f2bf((a0.w - m) * r * w0.w + b0.w);
    o[4] = (short)f2bf((a1.x - m) * r * w1.x + b1.x);
    o[5] = (short)f2bf((a1.y - m) * r * w1.y + b1.y);
    o[6] = (short)f2bf((a1.z - m) * r * w1.z + b1.z);
    o[7] = (short)f2bf((a1.w - m) * r * w1.w + b1.w);
    *(bf16x8*)(out + (size_t)row * HID + k0) = o;
}

__global__ void hnorm_kernel(const float* in, const float* mu, const float* rs,
                             const float* lw, const float* lb, u16* out, int NN) {
    hnorm_body(blockIdx.x * 256 + threadIdx.x, in, mu, rs, lw, lb, out, NN);
}

// ---------------------------------------------------------------------------
// Transpose fp32 weights to bf16 [n][k] for contiguous GEMM B-fragments.
// ---------------------------------------------------------------------------
__global__ void transpose_kernel(const float* w, const float* rootw,
                                 const float* w1, const float* w2,
                                 u16* WT, u16* rootT, u16* W1T, u16* W2T, int R) {
    int i = blockIdx.x * 256 + threadIdx.x;
    int nW = R * HID * HID;
    if (i < nW) {
        int r = i / (HID * HID); int rem = i % (HID * HID);
        int n = rem / HID, k = rem % HID;
        WT[i] = f2bf(w[r * HID * HID + k * HID + n]);
    } else if (i < nW + HID * HID) {
        int j = i - nW; int n = j / HID, k = j % HID;
        rootT[j] = f2bf(rootw[k * HID + n]);
    } else if (i < nW + HID * HID + FFD * HID) {
        int j = i - nW - HID * HID; int n = j / HID, k = j % HID;
        W1T[j] = f2bf(w1[k * FFD + n]);
    } else if (i < nW + HID * HID + FFD * HID + HID * FFD) {
        int j = i - nW - HID * HID - FFD * HID; int n = j / FFD, k = j % FFD;
        W2T[j] = f2bf(w2[k * HID + n]);
    }
}

// ---------------------------------------------------------------------------
// Fold W_r into attention vectors.
// ---------------------------------------------------------------------------
__global__ void vsd_kernel(const float* w, const float* att_src, const float* att_dst,
                           u16* Vsd, int R) {
    int idx = blockIdx.x * 256 + threadIdx.x;
    if (idx >= 64 * HID) return;
    int np = idx >> 7, k = idx & 127;
    int isDst = np >> 5, rh = np & 31, r = rh >> 2, h = rh & 3;
    const float* av = (isDst ? att_dst : att_src) + h * HD;
    const float* wp = w + (size_t)r * HID * HID + (size_t)k * HID + h * HD;
    float s = 0.f;
    #pragma unroll
    for (int d = 0; d < HD; d++) s += wp[d] * av[d];
    Vsd[idx] = f2bf(s);
}

__global__ void ae_kernel(const float* emb, const float* att_edge, float* ae, int R) {
    int i = threadIdx.x;
    if (i >= R * NH) return;
    int r = i >> 2, h = i & 3;
    float s = 0.f;
    #pragma unroll
    for (int d = 0; d < HD; d++)
        s += emb[r * HID + h * HD + d] * att_edge[h * HD + d];
    ae[i] = s;
}

// ---------------------------------------------------------------------------
// Register-resident-A GEMM for K=128, bf16 out.  TILED=1: 64x64 subtiles.
// EPI 0: raw bf16    EPI 2: +b1, exact gelu -> bf16
// ---------------------------------------------------------------------------
template <int EPI, int TILED>
__global__ __launch_bounds__(256)
void gemmy_kernel(const u16* Araw, const u16* BT, u16* Cout, const float* bias,
                  int M, int N, int aOff, int cOff, int ytiles) {
    int w = threadIdx.x >> 6, lane = threadIdx.x & 63;
    int l15 = lane & 15, quad = lane >> 4;
    int m0 = blockIdx.x * 64 + w * 16;
    int rowA = m0 + l15; if (rowA > M - 1) rowA = M - 1;
    const u16* ap = Araw + (size_t)(aOff + rowA) * HID + quad * 8;
    bf16x8 a[4];
    #pragma unroll
    for (int kk = 0; kk < 4; kk++) a[kk] = *(const bf16x8*)(ap + kk * 32);

    __shared__ u16 tile[64][72];
    int rl2 = threadIdx.x >> 3, seg = threadIdx.x & 7;
    int ybase = blockIdx.y * ytiles;
    int nsub = N >> 6;
    for (int yi = 0; yi < ytiles; yi++) {
        int n0 = (ybase + yi) * 64;
        f32x4 accr[4] = {};
        #pragma unroll
        for (int kk = 0; kk < 4; kk++) {
            #pragma unroll
            for (int t = 0; t < 4; t++) {
                const u16* bp = BT + (size_t)(n0 + t * 16 + l15) * HID + quad * 8 + kk * 32;
                bf16x8 bfrag = *(const bf16x8*)bp;
                accr[t] = __builtin_amdgcn_mfma_f32_16x16x32_bf16(a[kk], bfrag, accr[t], 0, 0, 0);
            }
        }
        if (yi > 0) __syncthreads();
        #pragma unroll
        for (int t = 0; t < 4; t++) {
            int col = n0 + t * 16 + l15;
            #pragma unroll
            for (int j = 0; j < 4; j++) {
                float v = accr[t][j];
                if constexpr (EPI == 2) {
                    v += bias[col];
                    v = 0.5f * v * (1.0f + erff(v * 0.70710678118654752f));
                }
                tile[w * 16 + quad * 4 + j][t * 16 + l15] = f2bf(v);
            }
        }
        __syncthreads();
        if constexpr (TILED) {
            u16* tb = Cout + (((size_t)blockIdx.x * nsub + (ybase + yi)) << 12);
            #pragma unroll
            for (int h = 0; h < 2; h++) {
                int rl = h * 32 + rl2;
                int row = blockIdx.x * 64 + rl;
                if (row < M) {
                    *(bf16x8*)(tb + (rl << 6) + seg * 8) =
                        *(const bf16x8*)&tile[rl][seg * 8];
                }
            }
        } else {
            #pragma unroll
            for (int h = 0; h < 2; h++) {
                int rl = h * 32 + rl2;
                int row = blockIdx.x * 64 + rl;
                if (row < M) {
                    u16* dst = Cout + (size_t)(cOff + row) * N + n0 + seg * 8;
                    *(bf16x8*)dst = *(const bf16x8*)&tile[rl][seg * 8];
                }
            }
        }
    }
}

// ---------------------------------------------------------------------------
// General MFMA GEMM, 64x64 block tile (epilogue variants as before).
// ---------------------------------------------------------------------------
template <int AM, int EPI>
__global__ __launch_bounds__(256)
void gemm_kernel(const void* Araw, const float* mu, const float* rs,
                 const float* lw, const float* lb,
                 const u16* BT, void* Cout, const float* bias,
                 const float* acc, const float* xin, const float* invden,
                 int M, int N, int K, int aOff, int cOff) {
    int w = threadIdx.x >> 6, lane = threadIdx.x & 63;
    int l15 = lane & 15, quad = lane >> 4;
    int m0 = blockIdx.x * 64 + w * 16;
    int n0 = blockIdx.y * 64;
    int rowA = m0 + l15; if (rowA > M - 1) rowA = M - 1;
    int gA = aOff + rowA;
    float muv = 0.f, rsv = 0.f;
    if (AM != 2) { muv = mu[gA]; rsv = rs[gA]; }

    f32x4 accr[4] = {};
    for (int kc = 0; kc < K; kc += 32) {
        bf16x8 a;
        if (AM == 0) {
            const float* ap = (const float*)Araw + (size_t)gA * K + quad * 8 + kc;
            float4 xa0 = *(const float4*)(ap);
            float4 xa1 = *(const float4*)(ap + 4);
            float4 w0 = *(const float4*)(lw + kc + quad * 8);
            float4 w1v = *(const float4*)(lw + kc + quad * 8 + 4);
            float4 b0 = *(const float4*)(lb + kc + quad * 8);
            float4 b1v = *(const float4*)(lb + kc + quad * 8 + 4);
            a[0] = (short)f2bf((xa0.x - muv) * rsv * w0.x + b0.x);
            a[1] = (short)f2bf((xa0.y - muv) * rsv * w0.y + b0.y);
            a[2] = (short)f2bf((xa0.z - muv) * rsv * w0.z + b0.z);
            a[3] = (short)f2bf((xa0.w - muv) * rsv * w0.w + b0.w);
            a[4] = (short)f2bf((xa1.x - muv) * rsv * w1v.x + b1v.x);
            a[5] = (short)f2bf((xa1.y - muv) * rsv * w1v.y + b1v.y);
            a[6] = (short)f2bf((xa1.z - muv) * rsv * w1v.z + b1v.z);
            a[7] = (short)f2bf((xa1.w - muv) * rsv * w1v.w + b1v.w);
        } else {
            const u16* ap = (const u16*)Araw + (size_t)gA * K + quad * 8 + kc;
            a = *(const bf16x8*)ap;
        }
        #pragma unroll
        for (int t = 0; t < 4; t++) {
            const u16* bp = BT + (size_t)(n0 + t * 16 + l15) * K + quad * 8 + kc;
            bf16x8 bfrag = *(const bf16x8*)bp;
            accr[t] = __builtin_amdgcn_mfma_f32_16x16x32_bf16(a, bfrag, accr[t], 0, 0, 0);
        }
    }

    if constexpr (EPI == 0 || EPI == 2) {
        __shared__ u16 tile[64][72];
        #pragma unroll
        for (int t = 0; t < 4; t++) {
            int col = n0 + t * 16 + l15;
            #pragma unroll
            for (int j = 0; j < 4; j++) {
                float v = accr[t][j];
                if (EPI == 2) {
                    v += bias[col];
                    v = 0.5f * v * (1.0f + erff(v * 0.70710678118654752f));
                }
                tile[w * 16 + quad * 4 + j][t * 16 + l15] = f2bf(v);
            }
        }
        __syncthreads();
        int rl2 = threadIdx.x >> 3, seg = threadIdx.x & 7;
        #pragma unroll
        for (int h = 0; h < 2; h++) {
            int rl = h * 32 + rl2;
            int row = blockIdx.x * 64 + rl;
            if (row < M) {
                u16* dst = (u16*)Cout + (size_t)(cOff + row) * N + n0 + seg * 8;
                *(bf16x8*)dst = *(const bf16x8*)&tile[rl][seg * 8];
            }
        }
    } else {
        #pragma unroll
        for (int t = 0; t < 4; t++) {
            int col = n0 + t * 16 + l15;
            #pragma unroll
            for (int j = 0; j < 4; j++) {
                int row = m0 + quad * 4 + j;
                if (row < M) {
                    float v = accr[t][j];
                    int grow = cOff + row;
                    size_t off = (size_t)grow * N + col;
                    if (EPI == 1) {
                        float msg = acc[(size_t)grow * HID + col]
                                  * invden[(size_t)grow * NH + (col >> 5)];
                        float o = v + msg + bias[col];
                        o = o > 0.f ? o : expm1f(o);
                        ((float*)Cout)[off] = xin[off] + o;
                    } else if (EPI == 3) {
                        ((float*)Cout)[off] = v + bias[col] + xin[off];
                    } else if (EPI == 5) {
                        float* tab = (float*)Cout;
                        if (col < 32) tab[(size_t)grow * 32 + col] = v;
                        else tab[(size_t)(M + grow) * 32 + (col - 32)] = v;
                    }
                }
            }
        }
    }
}

// ---------------------------------------------------------------------------
// CSR grouped by (dst, rel).
// ---------------------------------------------------------------------------
__global__ void deg_kernel(const int* ei, const int* et, int* deg2, int E, int NN) {
    int e = blockIdx.x * 256 + threadIdx.x;
    if (e >= E) return;
    int s = ei[e], d = ei[E + e], r = et[e];
    if ((unsigned)d < (unsigned)NN && (unsigned)r < (unsigned)RR &&
        (unsigned)s < (unsigned)NN)
        atomicAdd(&deg2[d * RR + r], 1);
}

__global__ void scan1_kernel(const int* in, int* out, int* bsum, int n) {
    __shared__ int buf[SCAN_B];
    int i = blockIdx.x * SCAN_B + threadIdx.x;
    int v = (i < n) ? in[i] : 0;
    buf[threadIdx.x] = v;
    __syncthreads();
    for (int s = 1; s < SCAN_B; s <<= 1) {
        int t = (threadIdx.x >= s) ? buf[threadIdx.x - s] : 0;
        __syncthreads();
        buf[threadIdx.x] += t;
        __syncthreads();
    }
    if (i < n) out[i] = buf[threadIdx.x] - v;
    if (threadIdx.x == SCAN_B - 1) bsum[blockIdx.x] = buf[SCAN_B - 1];
}

__global__ void scan2_kernel(int* bsum, int nb) {
    __shared__ int buf[SCAN_B];
    int v = (threadIdx.x < nb) ? bsum[threadIdx.x] : 0;
    buf[threadIdx.x] = v;
    __syncthreads();
    for (int s = 1; s < SCAN_B; s <<= 1) {
        int t = (threadIdx.x >= s) ? buf[threadIdx.x - s] : 0;
        __syncthreads();
        buf[threadIdx.x] += t;
        __syncthreads();
    }
    if (threadIdx.x < nb) bsum[threadIdx.x] = buf[threadIdx.x] - v;
    if (threadIdx.x == SCAN_B - 1) bsum[nb] = buf[SCAN_B - 1];
}

__global__ void scan3_kernel(int* out, int* curpos, const int* bsum, int n, int nb) {
    int i = blockIdx.x * SCAN_B + threadIdx.x;
    if (i < n) {
        int o = out[i] + bsum[blockIdx.x];
        out[i] = o; curpos[i] = o;
    }
    if (i == 0) out[n] = bsum[nb];
}

static __device__ __forceinline__
void fillA_body(int e, const int* ei, const int* et, const int* offs2,
                int* bcnt, u64* tmp, int E, int NN) {
    if (e >= E) return;
    int s = ei[e], d = ei[E + e], r = et[e];
    if ((unsigned)d >= (unsigned)NN || (unsigned)r >= (unsigned)RR ||
        (unsigned)s >= (unsigned)NN) return;
    int b = d >> NB_SH;
    int base = offs2[(b << NB_SH) * RR];
    int pos = atomicAdd(&bcnt[b * 16], 1);
    tmp[base + pos] = ((u64)d << 32) | (unsigned)((r << 24) | s);
}

__global__ void fillA_kernel(const int* ei, const int* et, const int* offs2,
                             int* bcnt, u64* tmp, int E, int NN) {
    fillA_body(blockIdx.x * 256 + threadIdx.x, ei, et, offs2, bcnt, tmp, E, NN);
}

__global__ void fillB_kernel(const u64* tmp, const int* offs2,
                             int* curpos2, int* rs_arr, int NN) {
    int b = blockIdx.x;
    int n0 = b << NB_SH;
    int n1 = n0 + (1 << NB_SH); if (n1 > NN) n1 = NN;
    int base = offs2[n0 * RR];
    int end  = offs2[n1 * RR];
    for (int i = base + threadIdx.x; i < end; i += 256) {
        u64 t = tmp[i];
        int d = (int)(t >> 32);
        unsigned v = (unsigned)t;
        int r = v >> 24;
        int pos = atomicAdd(&curpos2[d * RR + r], 1);
        rs_arr[pos] = (int)v;
    }
}

// ---------------------------------------------------------------------------
// wgt body (shared by wgt_kernel and fused2).
// ---------------------------------------------------------------------------
static __device__ __forceinline__
void wgt_body(int n, const int* offs2, const int* rs_arr,
              const float* asad, const float* ae,
              float* wgtb, float* invden, int NN) {
    if (n >= NN) return;
    int lane = threadIdx.x & 63;
    int el = lane >> 2, h = lane & 3;
    int p0 = offs2[n * RR], p1 = offs2[n * RR + RR];
    const float* ad = asad + (size_t)NN * 32;
    float base[RR];
    #pragma unroll
    for (int r = 0; r < RR; r++)
        base[r] = ad[(size_t)n * 32 + r * 4 + h] + ae[r * 4 + h];
    float mx = -1e30f;
    for (int p = p0 + el; p < p1; p += 16) {
        unsigned v = (unsigned)rs_arr[p];
        int r = v >> 24, s = v & 0xFFFFFF;
        float a = asad[(size_t)s * 32 + r * 4 + h] + base[r];
        a = a > 0.f ? a : 0.2f * a;
        wgtb[(size_t)p * NH + h] = a;
        mx = fmaxf(mx, a);
    }
    #pragma unroll
    for (int o = 4; o < 64; o <<= 1) mx = fmaxf(mx, __shfl_xor(mx, o, 64));
    float den = 0.f;
    for (int p = p0 + el; p < p1; p += 16) {
        float ex = __expf(wgtb[(size_t)p * NH + h] - mx);
        wgtb[(size_t)p * NH + h] = ex;
        den += ex;
    }
    #pragma unroll
    for (int o = 4; o < 64; o <<= 1) den += __shfl_xor(den, o, 64);
    if (el == 0) invden[n * NH + h] = 1.0f / (den + 1e-16f);
}

__global__ void wgt_kernel(const int* offs2, const int* rs_arr,
                           const float* asad, const float* ae,
                           float* wgtb, float* invden, int NN, int E) {
    wgt_body(blockIdx.x * 4 + (threadIdx.x >> 6), offs2, rs_arr, asad, ae,
             wgtb, invden, NN);
}

// ---------------------------------------------------------------------------
// FUSED 1: dots-GEMM (blocks [0,gxN)) || hnorm (next hB) || fillA (rest).
// All three are mutually independent once stats1 + scan3 are done.
// ---------------------------------------------------------------------------
__global__ __launch_bounds__(256)
void fused1_kernel(const float* x, const float* mu, const float* rs,
                   const float* lw, const float* lb, const u16* Vsd, float* asad,
                   u16* hb,
                   const int* ei, const int* et, const int* offs2,
                   int* bcnt, u64* tmp, int E, int NN, int gxN, int hB) {
    int bid = blockIdx.x;
    if (bid < gxN) {
        // dots: AM=0, EPI=5, N=64, K=128, n0=0
        int w = threadIdx.x >> 6, lane = threadIdx.x & 63;
        int l15 = lane & 15, quad = lane >> 4;
        int m0 = bid * 64 + w * 16;
        int rowA = m0 + l15; if (rowA > NN - 1) rowA = NN - 1;
        float muv = mu[rowA], rsv = rs[rowA];
        f32x4 accr[4] = {};
        for (int kc = 0; kc < HID; kc += 32) {
            const float* ap = x + (size_t)rowA * HID + quad * 8 + kc;
            float4 xa0 = *(const float4*)(ap);
            float4 xa1 = *(const float4*)(ap + 4);
            float4 w0 = *(const float4*)(lw + kc + quad * 8);
            float4 w1v = *(const float4*)(lw + kc + quad * 8 + 4);
            float4 b0 = *(const float4*)(lb + kc + quad * 8);
            float4 b1v = *(const float4*)(lb + kc + quad * 8 + 4);
            bf16x8 a;
            a[0] = (short)f2bf((xa0.x - muv) * rsv * w0.x + b0.x);
            a[1] = (short)f2bf((xa0.y - muv) * rsv * w0.y + b0.y);
            a[2] = (short)f2bf((xa0.z - muv) * rsv * w0.z + b0.z);
            a[3] = (short)f2bf((xa0.w - muv) * rsv * w0.w + b0.w);
            a[4] = (short)f2bf((xa1.x - muv) * rsv * w1v.x + b1v.x);
            a[5] = (short)f2bf((xa1.y - muv) * rsv * w1v.y + b1v.y);
            a[6] = (short)f2bf((xa1.z - muv) * rsv * w1v.z + b1v.z);
            a[7] = (short)f2bf((xa1.w - muv) * rsv * w1v.w + b1v.w);
            #pragma unroll
            for (int t = 0; t < 4; t++) {
                const u16* bp = Vsd + (size_t)(t * 16 + l15) * HID + quad * 8 + kc;
                bf16x8 bfrag = *(const bf16x8*)bp;
                accr[t] = __builtin_amdgcn_mfma_f32_16x16x32_bf16(a, bfrag, accr[t], 0, 0, 0);
            }
        }
        #pragma unroll
        for (int t = 0; t < 4; t++) {
            int col = t * 16 + l15;
            #pragma unroll
            for (int j = 0; j < 4; j++) {
                int row = m0 + quad * 4 + j;
                if (row < NN) {
                    float v = accr[t][j];
                    if (col < 32) asad[(size_t)row * 32 + col] = v;
                    else asad[(size_t)(NN + row) * 32 + (col - 32)] = v;
                }
            }
        }
    } else if (bid < gxN + hB) {
        hnorm_body((bid - gxN) * 256 + threadIdx.x, x, mu, rs, lw, lb, hb, NN);
    } else {
        fillA_body((bid - gxN - hB) * 256 + threadIdx.x, ei, et, offs2,
                   bcnt, tmp, E, NN);
    }
}

// ---------------------------------------------------------------------------
// FUSED 2: proj-GEMM (tiled xp, blocks [0,projB)) || wgt (rest).
// proj is write-drain-bound with idle pipes; wgt is gather-latency-bound --
// complementary resources, co-resident in one dispatch window.
// ---------------------------------------------------------------------------
__global__ __launch_bounds__(256)
void fused2_kernel(const u16* hb, const u16* WTw, u16* xp,
                   const int* offs2, const int* rs_arr, const float* asad,
                   const float* ae, float* wgtb, float* invden,
                   int NN, int gxN, int projB) {
    __shared__ u16 tile[64][72];
    int bid = blockIdx.x;
    if (bid < projB) {
        int xb = bid % gxN, yb = bid / gxN;
        int w = threadIdx.x >> 6, lane = threadIdx.x & 63;
        int l15 = lane & 15, quad = lane >> 4;
        int m0 = xb * 64 + w * 16;
        int rowA = m0 + l15; if (rowA > NN - 1) rowA = NN - 1;
        const u16* ap = hb + (size_t)rowA * HID + quad * 8;
        bf16x8 a[4];
        #pragma unroll
        for (int kk = 0; kk < 4; kk++) a[kk] = *(const bf16x8*)(ap + kk * 32);
        int rl2 = threadIdx.x >> 3, seg = threadIdx.x & 7;
        int ybase = yb * 8;
        for (int yi = 0; yi < 8; yi++) {
            int n0 = (ybase + yi) * 64;
            f32x4 accr[4] = {};
            #pragma unroll
            for (int kk = 0; kk < 4; kk++) {
                #pragma unroll
                for (int t = 0; t < 4; t++) {
                    const u16* bp = WTw + (size_t)(n0 + t * 16 + l15) * HID + quad * 8 + kk * 32;
                    bf16x8 bfrag = *(const bf16x8*)bp;
                    accr[t] = __builtin_amdgcn_mfma_f32_16x16x32_bf16(a[kk], bfrag, accr[t], 0, 0, 0);
                }
            }
            if (yi > 0) __syncthreads();
            #pragma unroll
            for (int t = 0; t < 4; t++) {
                #pragma unroll
                for (int j = 0; j < 4; j++) {
                    tile[w * 16 + quad * 4 + j][t * 16 + l15] = f2bf(accr[t][j]);
                }
            }
            __syncthreads();
            u16* tb = xp + (((size_t)xb * 16 + (ybase + yi)) << 12);
            #pragma unroll
            for (int h = 0; h < 2; h++) {
                int rl = h * 32 + rl2;
                int row = xb * 64 + rl;
                if (row < NN) {
                    *(bf16x8*)(tb + (rl << 6) + seg * 8) =
                        *(const bf16x8*)&tile[rl][seg * 8];
                }
            }
        }
    } else {
        wgt_body((bid - projB) * 4 + (threadIdx.x >> 6), offs2, rs_arr,
                 asad, ae, wgtb, invden, NN);
    }
}

// ---------------------------------------------------------------------------
// Single-pass message accumulation over TILED xp (unchanged from R15).
// ---------------------------------------------------------------------------
__global__ __launch_bounds__(256)
void msg1_kernel(const int* offs2, const int* rs_arr, const float* wgt,
                 const u16* xp, float* acc, int NN) {
    int n = blockIdx.x * 4 + (threadIdx.x >> 6);
    if (n >= NN) return;
    int lane = threadIdx.x & 63;
    int half = lane >> 5;
    int co = (lane & 31) << 1;
    int h = lane >> 4;
    int p0 = offs2[n * RR], p1 = offs2[n * RR + RR];
    float a0 = 0.f, a1 = 0.f;
    int p = p0;
    for (; p + 4 <= p1; p += 4) {
        unsigned v0 = (unsigned)rs_arr[p + 0];
        unsigned v1 = (unsigned)rs_arr[p + 1];
        unsigned v2 = (unsigned)rs_arr[p + 2];
        unsigned v3 = (unsigned)rs_arr[p + 3];
        unsigned s0 = v0 & 0xFFFFFFu, s1 = v1 & 0xFFFFFFu;
        unsigned s2 = v2 & 0xFFFFFFu, s3 = v3 & 0xFFFFFFu;
        unsigned z0 = *(const unsigned*)(xp
            + (((size_t)(s0 >> 6) * 16 + ((v0 >> 24) << 1) + half) << 12)
            + ((s0 & 63) << 6) + co);
        unsigned z1 = *(const unsigned*)(xp
            + (((size_t)(s1 >> 6) * 16 + ((v1 >> 24) << 1) + half) << 12)
            + ((s1 & 63) << 6) + co);
        unsigned z2 = *(const unsigned*)(xp
            + (((size_t)(s2 >> 6) * 16 + ((v2 >> 24) << 1) + half) << 12)
            + ((s2 & 63) << 6) + co);
        unsigned z3 = *(const unsigned*)(xp
            + (((size_t)(s3 >> 6) * 16 + ((v3 >> 24) << 1) + half) << 12)
            + ((s3 & 63) << 6) + co);
        float w0 = wgt[(size_t)(p + 0) * NH + h];
        float w1 = wgt[(size_t)(p + 1) * NH + h];
        float w2 = wgt[(size_t)(p + 2) * NH + h];
        float w3 = wgt[(size_t)(p + 3) * NH + h];
        a0 += w0 * bf2f((u16)z0) + w1 * bf2f((u16)z1)
            + w2 * bf2f((u16)z2) + w3 * bf2f((u16)z3);
        a1 += w0 * bf2f((u16)(z0 >> 16)) + w1 * bf2f((u16)(z1 >> 16))
            + w2 * bf2f((u16)(z2 >> 16)) + w3 * bf2f((u16)(z3 >> 16));
    }
    for (; p < p1; p++) {
        unsigned v = (unsigned)rs_arr[p];
        unsigned s = v & 0xFFFFFFu;
        unsigned z = *(const unsigned*)(xp
            + (((size_t)(s >> 6) * 16 + ((v >> 24) << 1) + half) << 12)
            + ((s & 63) << 6) + co);
        float wv = wgt[(size_t)p * NH + h];
        a0 += wv * bf2f((u16)z);
        a1 += wv * bf2f((u16)(z >> 16));
    }
    float2 o; o.x = a0; o.y = a1;
    *(float2*)(acc + (size_t)n * HID + (lane << 1)) = o;
}

// ---------------------------------------------------------------------------
// Multi-pass fallback (nrel < RR).
// ---------------------------------------------------------------------------
__global__ void msg2_kernel(const int* offs2, const int* rs_arr, const float* wgt,
                            const u16* xp, float* acc, int rc, int nrel, int ldx,
                            int NN, int E) {
    int n = blockIdx.x;
    int c = threadIdx.x, h = c >> 5;
    int p0 = offs2[n * RR + rc], p1 = offs2[n * RR + rc + nrel];
    if (p0 >= p1) return;
    float av = acc[(size_t)n * HID + c];
    for (int p = p0; p < p1; p++) {
        unsigned v = (unsigned)rs_arr[p];
        int r = (v >> 24) - rc;
        int s = v & 0xFFFFFF;
        av += wgt[(size_t)p * NH + h] * bf2f(xp[(size_t)s * ldx + r * HID + c]);
    }
    acc[(size_t)n * HID + c] = av;
}

// ---------------------------------------------------------------------------
extern "C" void kernel_launch(void* const* d_in, const int* in_sizes, int n_in,
                              void* d_out, int out_size, void* d_ws, size_t ws_size,
                              hipStream_t stream) {
    const float* x        = (const float*)d_in[0];
    const float* w        = (const float*)d_in[1];
    const float* rootw    = (const float*)d_in[2];
    const float* emb      = (const float*)d_in[3];
    const float* att_src  = (const float*)d_in[4];
    const float* att_dst  = (const float*)d_in[5];
    const float* att_edge = (const float*)d_in[6];
    const float* bias     = (const float*)d_in[7];
    const float* n1w      = (const float*)d_in[8];
    const float* n1b      = (const float*)d_in[9];
    const float* n2w      = (const float*)d_in[10];
    const float* n2b      = (const float*)d_in[11];
    const float* w1       = (const float*)d_in[12];
    const float* b1       = (const float*)d_in[13];
    const float* w2       = (const float*)d_in[14];
    const float* b2       = (const float*)d_in[15];
    const int* ei = (const int*)d_in[16];
    const int* et = (const int*)d_in[17];

    int NN = in_sizes[0] / HID;         // 50000
    int R  = in_sizes[1] / (HID * HID); // 8
    int E  = in_sizes[17];              // 800000
    int NR = NN * RR;
    int NBK = (NN + (1 << NB_SH) - 1) >> NB_SH;
    int gxN = (NN + 63) / 64;
    int Mpad = gxN * 64;

    // ---- arena ------------------------------------------------------------
    char* p = (char*)d_ws;
    auto alloc = [&](size_t bytes) -> char* {
        char* q = p; p += (bytes + 255) & ~(size_t)255; return q;
    };
    int* offs2   = (int*)alloc((size_t)(NR + 1) * 4);
    int* rs_arr  = (int*)alloc((size_t)E * 4);
    u16* WTw   = (u16*)alloc((size_t)R * HID * HID * 2);
    u16* rootT = (u16*)alloc((size_t)HID * HID * 2);
    u16* W1T   = (u16*)alloc((size_t)FFD * HID * 2);
    u16* W2T   = (u16*)alloc((size_t)HID * FFD * 2);
    u16* Vsd   = (u16*)alloc((size_t)64 * HID * 2);
    float* ae  = (float*)alloc((size_t)R * NH * 4);
    float* mu1 = (float*)alloc((size_t)NN * 4);
    float* rs1 = (float*)alloc((size_t)NN * 4);
    float* mu2 = (float*)alloc((size_t)NN * 4);
    float* rs2 = (float*)alloc((size_t)NN * 4);
    float* asad   = (float*)alloc((size_t)NN * 64 * 4);
    float* invden = (float*)alloc((size_t)NN * NH * 4);
    float* wgt    = (float*)alloc((size_t)E * NH * 4);
    float* acc    = (float*)alloc((size_t)NN * HID * 4);

    // CSR-build scratch aliases the (not-yet-live) wgt buffer (12.8MB).
    int nbScan = (NR + SCAN_B - 1) / SCAN_B;
    int* deg2    = (int*)wgt;
    int* curpos2 = deg2 + NR;
    int* bsum    = curpos2 + NR;
    int* bcnt    = bsum + nbScan + 1;
    u64* tmp     = (u64*)(((size_t)(bcnt + NBK * 16) + 7) & ~(size_t)7);

    // Tiered layout: 2 = fused (separate hbuf), 1 = serial single (aliased
    // hbuf), 0 = multi-rel fallback.
    size_t usedFixed = (size_t)(p - (char*)d_ws);
    size_t xpTiled = (size_t)Mpad * HID * RR * 2;
    size_t hbufSz  = (size_t)NN * HID * 2;
    int mode; int nrel = RR;
    u16 *xp, *hbuf;
    if (ws_size >= usedFixed + hbufSz + xpTiled + 512) {
        mode = 2;
        hbuf = (u16*)alloc(hbufSz);
        xp = (u16*)alloc(xpTiled);
    } else if (ws_size >= usedFixed + xpTiled + 256) {
        mode = 1;
        hbuf = (u16*)asad;
        xp = (u16*)alloc(xpTiled);
    } else {
        mode = 0;
        nrel = 1;
        for (int t = 4; t > 1; t >>= 1) {
            if (ws_size >= usedFixed + (size_t)NN * HID * t * 2 + 256) { nrel = t; break; }
        }
        hbuf = (u16*)asad;
        xp = (u16*)alloc((size_t)NN * HID * nrel * 2);
    }
    u16* u_ch = xp;                   // alias: FFN intermediate
    float* x2 = (float*)d_out;

    size_t used = (size_t)(p - (char*)d_ws);
    if (used > ws_size) {
        zeroout_kernel<<<(out_size + 255) / 256, 256, 0, stream>>>((float*)d_out, out_size);
        return;
    }

    // ---- phase 0: init, stats, weights, CSR scan --------------------------
    int initN = (mode != 0) ? (NR > NBK * 16 ? NR : NBK * 16) : NN * HID;
    init_kernel<<<(initN + 255) / 256, 256, 0, stream>>>(acc, deg2, bcnt, NN, NBK,
                                                         mode == 0 ? 1 : 0);
    stats_kernel<<<(NN + 3) / 4, 256, 0, stream>>>(x, mu1, rs1, NN);
    int nT = R * HID * HID + HID * HID + FFD * HID + HID * FFD;
    transpose_kernel<<<(nT + 255) / 256, 256, 0, stream>>>(w, rootw, w1, w2,
                                                           WTw, rootT, W1T, W2T, R);
    vsd_kernel<<<(64 * HID + 255) / 256, 256, 0, stream>>>(w, att_src, att_dst, Vsd, R);
    ae_kernel<<<1, 64, 0, stream>>>(emb, att_edge, ae, R);
    deg_kernel<<<(E + 255) / 256, 256, 0, stream>>>(ei, et, deg2, E, NN);
    scan1_kernel<<<nbScan, SCAN_B, 0, stream>>>(deg2, offs2, bsum, NR);
    scan2_kernel<<<1, SCAN_B, 0, stream>>>(bsum, nbScan);
    scan3_kernel<<<nbScan, SCAN_B, 0, stream>>>(offs2, curpos2, bsum, NR, nbScan);

    int hB = (NN * (HID / 8) + 255) / 256;
    int fB = (E + 255) / 256;

    if (mode == 2) {
        // fused1: dots || hnorm(separate hbuf) || fillA
        fused1_kernel<<<gxN + hB + fB, 256, 0, stream>>>(
            x, mu1, rs1, n1w, n1b, Vsd, asad, hbuf,
            ei, et, offs2, bcnt, tmp, E, NN, gxN, hB);
        fillB_kernel<<<NBK, 256, 0, stream>>>(tmp, offs2, curpos2, rs_arr, NN);
        // fused2: proj-GEMM (write-bound) || wgt (latency-bound)
        int projB = gxN * 2;
        int wB = (NN + 3) / 4;
        fused2_kernel<<<projB + wB, 256, 0, stream>>>(
            hbuf, WTw, xp, offs2, rs_arr, asad, ae, wgt, invden, NN, gxN, projB);
        msg1_kernel<<<(NN + 3) / 4, 256, 0, stream>>>(offs2, rs_arr, wgt, xp, acc, NN);
    } else {
        fillA_kernel<<<fB, 256, 0, stream>>>(ei, et, offs2, bcnt, tmp, E, NN);
        fillB_kernel<<<NBK, 256, 0, stream>>>(tmp, offs2, curpos2, rs_arr, NN);
        gemm_kernel<0, 5><<<dim3(gxN, 1), 256, 0, stream>>>(
            x, mu1, rs1, n1w, n1b, Vsd, asad,
            nullptr, nullptr, nullptr, nullptr, NN, 64, HID, 0, 0);
        wgt_kernel<<<(NN + 3) / 4, 256, 0, stream>>>(
            offs2, rs_arr, asad, ae, wgt, invden, NN, E);
        hnorm_kernel<<<hB, 256, 0, stream>>>(x, mu1, rs1, n1w, n1b, hbuf, NN);
        if (mode == 1) {
            gemmy_kernel<0, 1><<<dim3(gxN, 2), 256, 0, stream>>>(
                hbuf, WTw, xp, nullptr, NN, HID * RR, 0, 0, 8);
            msg1_kernel<<<(NN + 3) / 4, 256, 0, stream>>>(offs2, rs_arr, wgt, xp, acc, NN);
        } else {
            for (int rc = 0; rc < RR; rc += nrel) {
                gemm_kernel<2, 0><<<dim3(gxN, (HID * nrel) / 64), 256, 0, stream>>>(
                    hbuf, nullptr, nullptr, nullptr, nullptr, WTw + (size_t)rc * HID * HID,
                    xp, nullptr, nullptr, nullptr, nullptr, NN, HID * nrel, HID, 0, 0);
                msg2_kernel<<<NN, HID, 0, stream>>>(offs2, rs_arr, wgt, xp, acc,
                                                    rc, nrel, HID * nrel, NN, E);
            }
        }
    }

    // ---- phase 4: root gemm + msg*invden + bias + elu + residual -> x2 ----
    gemm_kernel<2, 1><<<dim3(gxN, HID / 64), 256, 0, stream>>>(
        hbuf, nullptr, nullptr, nullptr, nullptr, rootT, x2, bias, acc, x, invden,
        NN, HID, HID, 0, 0);

    // ---- phase 5: ln2 stats + hnorm2 + FFN --------------------------------
    stats_kernel<<<(NN + 3) / 4, 256, 0, stream>>>(x2, mu2, rs2, NN);
    hnorm_kernel<<<hB, 256, 0, stream>>>(x2, mu2, rs2, n2w, n2b, hbuf, NN);
    int nchunk = (mode != 0) ? 1 : (nrel >= 4 ? 1 : (nrel == 2 ? 2 : 4));
    int NCH = (NN + nchunk - 1) / nchunk;
    for (int j = 0; j < nchunk; j++) {
        int r0 = j * NCH;
        int Mc = NN - r0; if (Mc > NCH) Mc = NCH;
        if (Mc <= 0) continue;
        int gxc = (Mc + 63) / 64;
        gemmy_kernel<2, 0><<<dim3(gxc, 2), 256, 0, stream>>>(
            hbuf, W1T, u_ch, b1, Mc, FFD, r0, 0, 4);
        gemm_kernel<2, 3><<<dim3(gxc, HID / 64), 256, 0, stream>>>(
            u_ch, nullptr, nullptr, nullptr, nullptr, W2T, (float*)d_out, b2,
            nullptr, x2, nullptr, Mc, HID, FFD, 0, r0);
    }
}

// Round 17
// 575.219 us; speedup vs baseline: 1.3922x; 1.0223x over previous
//
#include <hip/hip_runtime.h>
#include <hip/hip_bf16.h>
#include <math.h>

#define HID 128
#define NH  4
#define HD  32
#define FFD 512
#define RR  8
#define SCAN_B 1024
#define NB_SH 6              // 64 dst nodes per scatter bucket

typedef __attribute__((ext_vector_type(8))) short bf16x8;
typedef __attribute__((ext_vector_type(4))) float f32x4;
typedef unsigned short u16;
typedef unsigned long long u64;

static __device__ __forceinline__ float bf2f(u16 u) {
    union { unsigned int i; float f; } v; v.i = ((unsigned int)u) << 16; return v.f;
}
static __device__ __forceinline__ u16 f2bf(float f) {
    union { float f; unsigned int i; } v; v.f = f;
    unsigned int x = v.i;
    return (u16)((x + 0x7fffu + ((x >> 16) & 1u)) >> 16);
}

__global__ void zeroout_kernel(float* out, int n) {
    int i = blockIdx.x * 256 + threadIdx.x;
    if (i < n) out[i] = 0.f;
}

__global__ void init_kernel(float* acc, int* deg2, int* bcnt, int NN, int NBK, int zacc) {
    int i = blockIdx.x * 256 + threadIdx.x;
    if (zacc && i < NN * HID) acc[i] = 0.f;
    if (i < NN * RR) deg2[i] = 0;
    if (i < NBK * 16) bcnt[i] = 0;
}

// ---------------------------------------------------------------------------
// Per-row LayerNorm stats (fp32 input).
// ---------------------------------------------------------------------------
__global__ void stats_kernel(const float* in, float* mu, float* rs, int NN) {
    int row = blockIdx.x * 4 + (threadIdx.x >> 6);
    int lane = threadIdx.x & 63;
    if (row >= NN) return;
    const float* p = in + (size_t)row * HID;
    float v0 = p[lane], v1 = p[lane + 64];
    float s = v0 + v1;
    #pragma unroll
    for (int o = 32; o > 0; o >>= 1) s += __shfl_xor(s, o, 64);
    float m = s * (1.0f / HID);
    float d0 = v0 - m, d1 = v1 - m;
    float q = d0 * d0 + d1 * d1;
    #pragma unroll
    for (int o = 32; o > 0; o >>= 1) q += __shfl_xor(q, o, 64);
    if (lane == 0) { mu[row] = m; rs[row] = rsqrtf(q * (1.0f / HID) + 1e-5f); }
}

// ---------------------------------------------------------------------------
// LN -> bf16 body (shared by hnorm_kernel and fused1).
// ---------------------------------------------------------------------------
static __device__ __forceinline__
void hnorm_body(int idx, const float* in, const float* mu, const float* rs,
                const float* lw, const float* lb, u16* out, int NN) {
    if (idx >= NN * (HID / 8)) return;
    int row = idx >> 4;
    int k0 = (idx & 15) * 8;
    float m = mu[row], r = rs[row];
    const float* p = in + (size_t)row * HID + k0;
    float4 a0 = *(const float4*)p, a1 = *(const float4*)(p + 4);
    float4 w0 = *(const float4*)(lw + k0), w1 = *(const float4*)(lw + k0 + 4);
    float4 b0 = *(const float4*)(lb + k0), b1 = *(const float4*)(lb + k0 + 4);
    bf16x8 o;
    o[0] = (short)f2bf((a0.x - m) * r * w0.x + b0.x);
    o[1] = (short)f2bf((a0.y - m) * r * w0.y + b0.y);
    o[2] = (short)f2bf((a0.z - m) * r * w0.z + b0.z);
    o[3] = (short)f2bf((a0.w - m) * r * w0.w + b0.w);
    o[4] = (short)f2bf((a1.x - m) * r * w1.x + b1.x);
    o[5] = (short)f2bf((a1.y - m) * r * w1.y + b1.y);
    o[6] = (short)f2bf((a1.z - m) * r * w1.z + b1.z);
    o[7] = (short)f2bf((a1.w - m) * r * w1.w + b1.w);
    *(bf16x8*)(out + (size_t)row * HID + k0) = o;
}

__global__ void hnorm_kernel(const float* in, const float* mu, const float* rs,
                             const float* lw, const float* lb, u16* out, int NN) {
    hnorm_body(blockIdx.x * 256 + threadIdx.x, in, mu, rs, lw, lb, out, NN);
}

// ---------------------------------------------------------------------------
// Transpose fp32 weights to bf16 [n][k].
// ---------------------------------------------------------------------------
__global__ void transpose_kernel(const float* w, const float* rootw,
                                 const float* w1, const float* w2,
                                 u16* WT, u16* rootT, u16* W1T, u16* W2T, int R) {
    int i = blockIdx.x * 256 + threadIdx.x;
    int nW = R * HID * HID;
    if (i < nW) {
        int r = i / (HID * HID); int rem = i % (HID * HID);
        int n = rem / HID, k = rem % HID;
        WT[i] = f2bf(w[r * HID * HID + k * HID + n]);
    } else if (i < nW + HID * HID) {
        int j = i - nW; int n = j / HID, k = j % HID;
        rootT[j] = f2bf(rootw[k * HID + n]);
    } else if (i < nW + HID * HID + FFD * HID) {
        int j = i - nW - HID * HID; int n = j / HID, k = j % HID;
        W1T[j] = f2bf(w1[k * FFD + n]);
    } else if (i < nW + HID * HID + FFD * HID + HID * FFD) {
        int j = i - nW - HID * HID - FFD * HID; int n = j / FFD, k = j % FFD;
        W2T[j] = f2bf(w2[k * HID + n]);
    }
}

__global__ void vsd_kernel(const float* w, const float* att_src, const float* att_dst,
                           u16* Vsd, int R) {
    int idx = blockIdx.x * 256 + threadIdx.x;
    if (idx >= 64 * HID) return;
    int np = idx >> 7, k = idx & 127;
    int isDst = np >> 5, rh = np & 31, r = rh >> 2, h = rh & 3;
    const float* av = (isDst ? att_dst : att_src) + h * HD;
    const float* wp = w + (size_t)r * HID * HID + (size_t)k * HID + h * HD;
    float s = 0.f;
    #pragma unroll
    for (int d = 0; d < HD; d++) s += wp[d] * av[d];
    Vsd[idx] = f2bf(s);
}

__global__ void ae_kernel(const float* emb, const float* att_edge, float* ae, int R) {
    int i = threadIdx.x;
    if (i >= R * NH) return;
    int r = i >> 2, h = i & 3;
    float s = 0.f;
    #pragma unroll
    for (int d = 0; d < HD; d++)
        s += emb[r * HID + h * HD + d] * att_edge[h * HD + d];
    ae[i] = s;
}

// ---------------------------------------------------------------------------
// Register-resident-A GEMM for K=128, bf16 out.  TILED=1: 64x64 subtiles.
// EPI 0: raw bf16    EPI 2: +b1, exact gelu -> bf16
// ---------------------------------------------------------------------------
template <int EPI, int TILED>
__global__ __launch_bounds__(256)
void gemmy_kernel(const u16* Araw, const u16* BT, u16* Cout, const float* bias,
                  int M, int N, int aOff, int cOff, int ytiles) {
    int w = threadIdx.x >> 6, lane = threadIdx.x & 63;
    int l15 = lane & 15, quad = lane >> 4;
    int m0 = blockIdx.x * 64 + w * 16;
    int rowA = m0 + l15; if (rowA > M - 1) rowA = M - 1;
    const u16* ap = Araw + (size_t)(aOff + rowA) * HID + quad * 8;
    bf16x8 a[4];
    #pragma unroll
    for (int kk = 0; kk < 4; kk++) a[kk] = *(const bf16x8*)(ap + kk * 32);

    __shared__ u16 tile[64][72];
    int rl2 = threadIdx.x >> 3, seg = threadIdx.x & 7;
    int ybase = blockIdx.y * ytiles;
    int nsub = N >> 6;
    for (int yi = 0; yi < ytiles; yi++) {
        int n0 = (ybase + yi) * 64;
        f32x4 accr[4] = {};
        #pragma unroll
        for (int kk = 0; kk < 4; kk++) {
            #pragma unroll
            for (int t = 0; t < 4; t++) {
                const u16* bp = BT + (size_t)(n0 + t * 16 + l15) * HID + quad * 8 + kk * 32;
                bf16x8 bfrag = *(const bf16x8*)bp;
                accr[t] = __builtin_amdgcn_mfma_f32_16x16x32_bf16(a[kk], bfrag, accr[t], 0, 0, 0);
            }
        }
        if (yi > 0) __syncthreads();
        #pragma unroll
        for (int t = 0; t < 4; t++) {
            int col = n0 + t * 16 + l15;
            #pragma unroll
            for (int j = 0; j < 4; j++) {
                float v = accr[t][j];
                if constexpr (EPI == 2) {
                    v += bias[col];
                    v = 0.5f * v * (1.0f + erff(v * 0.70710678118654752f));
                }
                tile[w * 16 + quad * 4 + j][t * 16 + l15] = f2bf(v);
            }
        }
        __syncthreads();
        if constexpr (TILED) {
            u16* tb = Cout + (((size_t)blockIdx.x * nsub + (ybase + yi)) << 12);
            #pragma unroll
            for (int h = 0; h < 2; h++) {
                int rl = h * 32 + rl2;
                int row = blockIdx.x * 64 + rl;
                if (row < M) {
                    *(bf16x8*)(tb + (rl << 6) + seg * 8) =
                        *(const bf16x8*)&tile[rl][seg * 8];
                }
            }
        } else {
            #pragma unroll
            for (int h = 0; h < 2; h++) {
                int rl = h * 32 + rl2;
                int row = blockIdx.x * 64 + rl;
                if (row < M) {
                    u16* dst = Cout + (size_t)(cOff + row) * N + n0 + seg * 8;
                    *(bf16x8*)dst = *(const bf16x8*)&tile[rl][seg * 8];
                }
            }
        }
    }
}

// ---------------------------------------------------------------------------
// General MFMA GEMM (epilogue variants as before).
// ---------------------------------------------------------------------------
template <int AM, int EPI>
__global__ __launch_bounds__(256)
void gemm_kernel(const void* Araw, const float* mu, const float* rs,
                 const float* lw, const float* lb,
                 const u16* BT, void* Cout, const float* bias,
                 const float* acc, const float* xin, const float* invden,
                 int M, int N, int K, int aOff, int cOff) {
    int w = threadIdx.x >> 6, lane = threadIdx.x & 63;
    int l15 = lane & 15, quad = lane >> 4;
    int m0 = blockIdx.x * 64 + w * 16;
    int n0 = blockIdx.y * 64;
    int rowA = m0 + l15; if (rowA > M - 1) rowA = M - 1;
    int gA = aOff + rowA;
    float muv = 0.f, rsv = 0.f;
    if (AM != 2) { muv = mu[gA]; rsv = rs[gA]; }

    f32x4 accr[4] = {};
    for (int kc = 0; kc < K; kc += 32) {
        bf16x8 a;
        if (AM == 0) {
            const float* ap = (const float*)Araw + (size_t)gA * K + quad * 8 + kc;
            float4 xa0 = *(const float4*)(ap);
            float4 xa1 = *(const float4*)(ap + 4);
            float4 w0 = *(const float4*)(lw + kc + quad * 8);
            float4 w1v = *(const float4*)(lw + kc + quad * 8 + 4);
            float4 b0 = *(const float4*)(lb + kc + quad * 8);
            float4 b1v = *(const float4*)(lb + kc + quad * 8 + 4);
            a[0] = (short)f2bf((xa0.x - muv) * rsv * w0.x + b0.x);
            a[1] = (short)f2bf((xa0.y - muv) * rsv * w0.y + b0.y);
            a[2] = (short)f2bf((xa0.z - muv) * rsv * w0.z + b0.z);
            a[3] = (short)f2bf((xa0.w - muv) * rsv * w0.w + b0.w);
            a[4] = (short)f2bf((xa1.x - muv) * rsv * w1v.x + b1v.x);
            a[5] = (short)f2bf((xa1.y - muv) * rsv * w1v.y + b1v.y);
            a[6] = (short)f2bf((xa1.z - muv) * rsv * w1v.z + b1v.z);
            a[7] = (short)f2bf((xa1.w - muv) * rsv * w1v.w + b1v.w);
        } else {
            const u16* ap = (const u16*)Araw + (size_t)gA * K + quad * 8 + kc;
            a = *(const bf16x8*)ap;
        }
        #pragma unroll
        for (int t = 0; t < 4; t++) {
            const u16* bp = BT + (size_t)(n0 + t * 16 + l15) * K + quad * 8 + kc;
            bf16x8 bfrag = *(const bf16x8*)bp;
            accr[t] = __builtin_amdgcn_mfma_f32_16x16x32_bf16(a, bfrag, accr[t], 0, 0, 0);
        }
    }

    if constexpr (EPI == 0 || EPI == 2) {
        __shared__ u16 tile[64][72];
        #pragma unroll
        for (int t = 0; t < 4; t++) {
            int col = n0 + t * 16 + l15;
            #pragma unroll
            for (int j = 0; j < 4; j++) {
                float v = accr[t][j];
                if (EPI == 2) {
                    v += bias[col];
                    v = 0.5f * v * (1.0f + erff(v * 0.70710678118654752f));
                }
                tile[w * 16 + quad * 4 + j][t * 16 + l15] = f2bf(v);
            }
        }
        __syncthreads();
        int rl2 = threadIdx.x >> 3, seg = threadIdx.x & 7;
        #pragma unroll
        for (int h = 0; h < 2; h++) {
            int rl = h * 32 + rl2;
            int row = blockIdx.x * 64 + rl;
            if (row < M) {
                u16* dst = (u16*)Cout + (size_t)(cOff + row) * N + n0 + seg * 8;
                *(bf16x8*)dst = *(const bf16x8*)&tile[rl][seg * 8];
            }
        }
    } else {
        #pragma unroll
        for (int t = 0; t < 4; t++) {
            int col = n0 + t * 16 + l15;
            #pragma unroll
            for (int j = 0; j < 4; j++) {
                int row = m0 + quad * 4 + j;
                if (row < M) {
                    float v = accr[t][j];
                    int grow = cOff + row;
                    size_t off = (size_t)grow * N + col;
                    if (EPI == 1) {
                        float msg = acc[(size_t)grow * HID + col]
                                  * invden[(size_t)grow * NH + (col >> 5)];
                        float o = v + msg + bias[col];
                        o = o > 0.f ? o : expm1f(o);
                        ((float*)Cout)[off] = xin[off] + o;
                    } else if (EPI == 3) {
                        ((float*)Cout)[off] = v + bias[col] + xin[off];
                    } else if (EPI == 5) {
                        float* tab = (float*)Cout;
                        if (col < 32) tab[(size_t)grow * 32 + col] = v;
                        else tab[(size_t)(M + grow) * 32 + (col - 32)] = v;
                    }
                }
            }
        }
    }
}

// ---------------------------------------------------------------------------
// CSR grouped by (dst, rel).
// ---------------------------------------------------------------------------
__global__ void deg_kernel(const int* ei, const int* et, int* deg2, int E, int NN) {
    int e = blockIdx.x * 256 + threadIdx.x;
    if (e >= E) return;
    int s = ei[e], d = ei[E + e], r = et[e];
    if ((unsigned)d < (unsigned)NN && (unsigned)r < (unsigned)RR &&
        (unsigned)s < (unsigned)NN)
        atomicAdd(&deg2[d * RR + r], 1);
}

__global__ void scan1_kernel(const int* in, int* out, int* bsum, int n) {
    __shared__ int buf[SCAN_B];
    int i = blockIdx.x * SCAN_B + threadIdx.x;
    int v = (i < n) ? in[i] : 0;
    buf[threadIdx.x] = v;
    __syncthreads();
    for (int s = 1; s < SCAN_B; s <<= 1) {
        int t = (threadIdx.x >= s) ? buf[threadIdx.x - s] : 0;
        __syncthreads();
        buf[threadIdx.x] += t;
        __syncthreads();
    }
    if (i < n) out[i] = buf[threadIdx.x] - v;
    if (threadIdx.x == SCAN_B - 1) bsum[blockIdx.x] = buf[SCAN_B - 1];
}

__global__ void scan2_kernel(int* bsum, int nb) {
    __shared__ int buf[SCAN_B];
    int v = (threadIdx.x < nb) ? bsum[threadIdx.x] : 0;
    buf[threadIdx.x] = v;
    __syncthreads();
    for (int s = 1; s < SCAN_B; s <<= 1) {
        int t = (threadIdx.x >= s) ? buf[threadIdx.x - s] : 0;
        __syncthreads();
        buf[threadIdx.x] += t;
        __syncthreads();
    }
    if (threadIdx.x < nb) bsum[threadIdx.x] = buf[threadIdx.x] - v;
    if (threadIdx.x == SCAN_B - 1) bsum[nb] = buf[SCAN_B - 1];
}

__global__ void scan3_kernel(int* out, int* curpos, const int* bsum, int n, int nb) {
    int i = blockIdx.x * SCAN_B + threadIdx.x;
    if (i < n) {
        int o = out[i] + bsum[blockIdx.x];
        out[i] = o; curpos[i] = o;
    }
    if (i == 0) out[n] = bsum[nb];
}

static __device__ __forceinline__
void fillA_body(int e, const int* ei, const int* et, const int* offs2,
                int* bcnt, u64* tmp, int E, int NN) {
    if (e >= E) return;
    int s = ei[e], d = ei[E + e], r = et[e];
    if ((unsigned)d >= (unsigned)NN || (unsigned)r >= (unsigned)RR ||
        (unsigned)s >= (unsigned)NN) return;
    int b = d >> NB_SH;
    int base = offs2[(b << NB_SH) * RR];
    int pos = atomicAdd(&bcnt[b * 16], 1);
    tmp[base + pos] = ((u64)d << 32) | (unsigned)((r << 24) | s);
}

__global__ void fillA_kernel(const int* ei, const int* et, const int* offs2,
                             int* bcnt, u64* tmp, int E, int NN) {
    fillA_body(blockIdx.x * 256 + threadIdx.x, ei, et, offs2, bcnt, tmp, E, NN);
}

__global__ void fillB_kernel(const u64* tmp, const int* offs2,
                             int* curpos2, int* rs_arr, int NN) {
    int b = blockIdx.x;
    int n0 = b << NB_SH;
    int n1 = n0 + (1 << NB_SH); if (n1 > NN) n1 = NN;
    int base = offs2[n0 * RR];
    int end  = offs2[n1 * RR];
    for (int i = base + threadIdx.x; i < end; i += 256) {
        u64 t = tmp[i];
        int d = (int)(t >> 32);
        unsigned v = (unsigned)t;
        int r = v >> 24;
        int pos = atomicAdd(&curpos2[d * RR + r], 1);
        rs_arr[pos] = (int)v;
    }
}

// ---------------------------------------------------------------------------
// wgt body (shared by wgt_kernel and fused2).
// ---------------------------------------------------------------------------
static __device__ __forceinline__
void wgt_body(int n, const int* offs2, const int* rs_arr,
              const float* asad, const float* ae,
              float* wgtb, float* invden, int NN) {
    if (n >= NN) return;
    int lane = threadIdx.x & 63;
    int el = lane >> 2, h = lane & 3;
    int p0 = offs2[n * RR], p1 = offs2[n * RR + RR];
    const float* ad = asad + (size_t)NN * 32;
    float base[RR];
    #pragma unroll
    for (int r = 0; r < RR; r++)
        base[r] = ad[(size_t)n * 32 + r * 4 + h] + ae[r * 4 + h];
    float mx = -1e30f;
    for (int p = p0 + el; p < p1; p += 16) {
        unsigned v = (unsigned)rs_arr[p];
        int r = v >> 24, s = v & 0xFFFFFF;
        float a = asad[(size_t)s * 32 + r * 4 + h] + base[r];
        a = a > 0.f ? a : 0.2f * a;
        wgtb[(size_t)p * NH + h] = a;
        mx = fmaxf(mx, a);
    }
    #pragma unroll
    for (int o = 4; o < 64; o <<= 1) mx = fmaxf(mx, __shfl_xor(mx, o, 64));
    float den = 0.f;
    for (int p = p0 + el; p < p1; p += 16) {
        float ex = __expf(wgtb[(size_t)p * NH + h] - mx);
        wgtb[(size_t)p * NH + h] = ex;
        den += ex;
    }
    #pragma unroll
    for (int o = 4; o < 64; o <<= 1) den += __shfl_xor(den, o, 64);
    if (el == 0) invden[n * NH + h] = 1.0f / (den + 1e-16f);
}

__global__ void wgt_kernel(const int* offs2, const int* rs_arr,
                           const float* asad, const float* ae,
                           float* wgtb, float* invden, int NN, int E) {
    wgt_body(blockIdx.x * 4 + (threadIdx.x >> 6), offs2, rs_arr, asad, ae,
             wgtb, invden, NN);
}

// ---------------------------------------------------------------------------
// FUSED 1: dots-GEMM || hnorm || fillA.
// ---------------------------------------------------------------------------
__global__ __launch_bounds__(256)
void fused1_kernel(const float* x, const float* mu, const float* rs,
                   const float* lw, const float* lb, const u16* Vsd, float* asad,
                   u16* hb,
                   const int* ei, const int* et, const int* offs2,
                   int* bcnt, u64* tmp, int E, int NN, int gxN, int hB) {
    int bid = blockIdx.x;
    if (bid < gxN) {
        int w = threadIdx.x >> 6, lane = threadIdx.x & 63;
        int l15 = lane & 15, quad = lane >> 4;
        int m0 = bid * 64 + w * 16;
        int rowA = m0 + l15; if (rowA > NN - 1) rowA = NN - 1;
        float muv = mu[rowA], rsv = rs[rowA];
        f32x4 accr[4] = {};
        for (int kc = 0; kc < HID; kc += 32) {
            const float* ap = x + (size_t)rowA * HID + quad * 8 + kc;
            float4 xa0 = *(const float4*)(ap);
            float4 xa1 = *(const float4*)(ap + 4);
            float4 w0 = *(const float4*)(lw + kc + quad * 8);
            float4 w1v = *(const float4*)(lw + kc + quad * 8 + 4);
            float4 b0 = *(const float4*)(lb + kc + quad * 8);
            float4 b1v = *(const float4*)(lb + kc + quad * 8 + 4);
            bf16x8 a;
            a[0] = (short)f2bf((xa0.x - muv) * rsv * w0.x + b0.x);
            a[1] = (short)f2bf((xa0.y - muv) * rsv * w0.y + b0.y);
            a[2] = (short)f2bf((xa0.z - muv) * rsv * w0.z + b0.z);
            a[3] = (short)f2bf((xa0.w - muv) * rsv * w0.w + b0.w);
            a[4] = (short)f2bf((xa1.x - muv) * rsv * w1v.x + b1v.x);
            a[5] = (short)f2bf((xa1.y - muv) * rsv * w1v.y + b1v.y);
            a[6] = (short)f2bf((xa1.z - muv) * rsv * w1v.z + b1v.z);
            a[7] = (short)f2bf((xa1.w - muv) * rsv * w1v.w + b1v.w);
            #pragma unroll
            for (int t = 0; t < 4; t++) {
                const u16* bp = Vsd + (size_t)(t * 16 + l15) * HID + quad * 8 + kc;
                bf16x8 bfrag = *(const bf16x8*)bp;
                accr[t] = __builtin_amdgcn_mfma_f32_16x16x32_bf16(a, bfrag, accr[t], 0, 0, 0);
            }
        }
        #pragma unroll
        for (int t = 0; t < 4; t++) {
            int col = t * 16 + l15;
            #pragma unroll
            for (int j = 0; j < 4; j++) {
                int row = m0 + quad * 4 + j;
                if (row < NN) {
                    float v = accr[t][j];
                    if (col < 32) asad[(size_t)row * 32 + col] = v;
                    else asad[(size_t)(NN + row) * 32 + (col - 32)] = v;
                }
            }
        }
    } else if (bid < gxN + hB) {
        hnorm_body((bid - gxN) * 256 + threadIdx.x, x, mu, rs, lw, lb, hb, NN);
    } else {
        fillA_body((bid - gxN - hB) * 256 + threadIdx.x, ei, et, offs2,
                   bcnt, tmp, E, NN);
    }
}

// ---------------------------------------------------------------------------
// FUSED 2: proj-GEMM (tiled xp) || wgt.
// ---------------------------------------------------------------------------
__global__ __launch_bounds__(256)
void fused2_kernel(const u16* hb, const u16* WTw, u16* xp,
                   const int* offs2, const int* rs_arr, const float* asad,
                   const float* ae, float* wgtb, float* invden,
                   int NN, int gxN, int projB) {
    __shared__ u16 tile[64][72];
    int bid = blockIdx.x;
    if (bid < projB) {
        int xb = bid % gxN, yb = bid / gxN;
        int w = threadIdx.x >> 6, lane = threadIdx.x & 63;
        int l15 = lane & 15, quad = lane >> 4;
        int m0 = xb * 64 + w * 16;
        int rowA = m0 + l15; if (rowA > NN - 1) rowA = NN - 1;
        const u16* ap = hb + (size_t)rowA * HID + quad * 8;
        bf16x8 a[4];
        #pragma unroll
        for (int kk = 0; kk < 4; kk++) a[kk] = *(const bf16x8*)(ap + kk * 32);
        int rl2 = threadIdx.x >> 3, seg = threadIdx.x & 7;
        int ybase = yb * 8;
        for (int yi = 0; yi < 8; yi++) {
            int n0 = (ybase + yi) * 64;
            f32x4 accr[4] = {};
            #pragma unroll
            for (int kk = 0; kk < 4; kk++) {
                #pragma unroll
                for (int t = 0; t < 4; t++) {
                    const u16* bp = WTw + (size_t)(n0 + t * 16 + l15) * HID + quad * 8 + kk * 32;
                    bf16x8 bfrag = *(const bf16x8*)bp;
                    accr[t] = __builtin_amdgcn_mfma_f32_16x16x32_bf16(a[kk], bfrag, accr[t], 0, 0, 0);
                }
            }
            if (yi > 0) __syncthreads();
            #pragma unroll
            for (int t = 0; t < 4; t++) {
                #pragma unroll
                for (int j = 0; j < 4; j++) {
                    tile[w * 16 + quad * 4 + j][t * 16 + l15] = f2bf(accr[t][j]);
                }
            }
            __syncthreads();
            u16* tb = xp + (((size_t)xb * 16 + (ybase + yi)) << 12);
            #pragma unroll
            for (int h = 0; h < 2; h++) {
                int rl = h * 32 + rl2;
                int row = xb * 64 + rl;
                if (row < NN) {
                    *(bf16x8*)(tb + (rl << 6) + seg * 8) =
                        *(const bf16x8*)&tile[rl][seg * 8];
                }
            }
        }
    } else {
        wgt_body((bid - projB) * 4 + (threadIdx.x >> 6), offs2, rs_arr,
                 asad, ae, wgtb, invden, NN);
    }
}

// ---------------------------------------------------------------------------
// FUSED 3: root-projection (blocks [0,2*gxN): rootp = hbuf@rootT, bf16
// untiled [NN][128], ~13MB write hidden under msg1) || msg1 (rest).
// ---------------------------------------------------------------------------
__global__ __launch_bounds__(256)
void fused3_kernel(const u16* hb, const u16* rootT, u16* rootp,
                   const int* offs2, const int* rs_arr, const float* wgtb,
                   const u16* xp, float* acc, int NN, int gxN) {
    __shared__ u16 tile[64][72];
    int bid = blockIdx.x;
    if (bid < 2 * gxN) {
        int xb = bid >> 1, yb = bid & 1;
        int w = threadIdx.x >> 6, lane = threadIdx.x & 63;
        int l15 = lane & 15, quad = lane >> 4;
        int m0 = xb * 64 + w * 16;
        int rowA = m0 + l15; if (rowA > NN - 1) rowA = NN - 1;
        const u16* ap = hb + (size_t)rowA * HID + quad * 8;
        bf16x8 a[4];
        #pragma unroll
        for (int kk = 0; kk < 4; kk++) a[kk] = *(const bf16x8*)(ap + kk * 32);
        int n0 = yb * 64;
        f32x4 accr[4] = {};
        #pragma unroll
        for (int kk = 0; kk < 4; kk++) {
            #pragma unroll
            for (int t = 0; t < 4; t++) {
                const u16* bp = rootT + (size_t)(n0 + t * 16 + l15) * HID + quad * 8 + kk * 32;
                bf16x8 bfrag = *(const bf16x8*)bp;
                accr[t] = __builtin_amdgcn_mfma_f32_16x16x32_bf16(a[kk], bfrag, accr[t], 0, 0, 0);
            }
        }
        #pragma unroll
        for (int t = 0; t < 4; t++) {
            #pragma unroll
            for (int j = 0; j < 4; j++) {
                tile[w * 16 + quad * 4 + j][t * 16 + l15] = f2bf(accr[t][j]);
            }
        }
        __syncthreads();
        int rl2 = threadIdx.x >> 3, seg = threadIdx.x & 7;
        #pragma unroll
        for (int h = 0; h < 2; h++) {
            int rl = h * 32 + rl2;
            int row = xb * 64 + rl;
            if (row < NN) {
                u16* dst = rootp + (size_t)row * HID + n0 + seg * 8;
                *(bf16x8*)dst = *(const bf16x8*)&tile[rl][seg * 8];
            }
        }
    } else {
        // msg1 body (tiled xp)
        int n = (bid - 2 * gxN) * 4 + (threadIdx.x >> 6);
        if (n >= NN) return;
        int lane = threadIdx.x & 63;
        int half = lane >> 5;
        int co = (lane & 31) << 1;
        int h = lane >> 4;
        int p0 = offs2[n * RR], p1 = offs2[n * RR + RR];
        float a0 = 0.f, a1 = 0.f;
        int p = p0;
        for (; p + 4 <= p1; p += 4) {
            unsigned v0 = (unsigned)rs_arr[p + 0];
            unsigned v1 = (unsigned)rs_arr[p + 1];
            unsigned v2 = (unsigned)rs_arr[p + 2];
            unsigned v3 = (unsigned)rs_arr[p + 3];
            unsigned s0 = v0 & 0xFFFFFFu, s1 = v1 & 0xFFFFFFu;
            unsigned s2 = v2 & 0xFFFFFFu, s3 = v3 & 0xFFFFFFu;
            unsigned z0 = *(const unsigned*)(xp
                + (((size_t)(s0 >> 6) * 16 + ((v0 >> 24) << 1) + half) << 12)
                + ((s0 & 63) << 6) + co);
            unsigned z1 = *(const unsigned*)(xp
                + (((size_t)(s1 >> 6) * 16 + ((v1 >> 24) << 1) + half) << 12)
                + ((s1 & 63) << 6) + co);
            unsigned z2 = *(const unsigned*)(xp
                + (((size_t)(s2 >> 6) * 16 + ((v2 >> 24) << 1) + half) << 12)
                + ((s2 & 63) << 6) + co);
            unsigned z3 = *(const unsigned*)(xp
                + (((size_t)(s3 >> 6) * 16 + ((v3 >> 24) << 1) + half) << 12)
                + ((s3 & 63) << 6) + co);
            float w0 = wgtb[(size_t)(p + 0) * NH + h];
            float w1 = wgtb[(size_t)(p + 1) * NH + h];
            float w2 = wgtb[(size_t)(p + 2) * NH + h];
            float w3 = wgtb[(size_t)(p + 3) * NH + h];
            a0 += w0 * bf2f((u16)z0) + w1 * bf2f((u16)z1)
                + w2 * bf2f((u16)z2) + w3 * bf2f((u16)z3);
            a1 += w0 * bf2f((u16)(z0 >> 16)) + w1 * bf2f((u16)(z1 >> 16))
                + w2 * bf2f((u16)(z2 >> 16)) + w3 * bf2f((u16)(z3 >> 16));
        }
        for (; p < p1; p++) {
            unsigned v = (unsigned)rs_arr[p];
            unsigned s = v & 0xFFFFFFu;
            unsigned z = *(const unsigned*)(xp
                + (((size_t)(s >> 6) * 16 + ((v >> 24) << 1) + half) << 12)
                + ((s & 63) << 6) + co);
            float wv = wgtb[(size_t)p * NH + h];
            a0 += wv * bf2f((u16)z);
            a1 += wv * bf2f((u16)(z >> 16));
        }
        float2 o; o.x = a0; o.y = a1;
        *(float2*)(acc + (size_t)n * HID + (lane << 1)) = o;
    }
}

// ---------------------------------------------------------------------------
// EPI2: one wave per row.  o = elu(rootp + acc*invden + bias); x2 = x + o;
// then in-register LN2 (wave reduce) -> hbuf bf16.  Replaces root-GEMM EPI1
// + stats2 + hnorm2 (3 passes -> 1).
// ---------------------------------------------------------------------------
__global__ __launch_bounds__(256)
void epi2_kernel(const u16* rootp, const float* acc, const float* invden,
                 const float* bias, const float* x, float* x2,
                 const float* n2w, const float* n2b, u16* hb, int NN) {
    int row = blockIdx.x * 4 + (threadIdx.x >> 6);
    if (row >= NN) return;
    int lane = threadIdx.x & 63;
    int c2 = lane << 1;
    unsigned rp = *(const unsigned*)(rootp + (size_t)row * HID + c2);
    float2 av = *(const float2*)(acc + (size_t)row * HID + c2);
    float inv = invden[row * NH + (lane >> 4)];
    float2 bv = *(const float2*)(bias + c2);
    float2 xv = *(const float2*)(x + (size_t)row * HID + c2);
    float o0 = bf2f((u16)rp) + av.x * inv + bv.x;
    float o1 = bf2f((u16)(rp >> 16)) + av.y * inv + bv.y;
    o0 = o0 > 0.f ? o0 : expm1f(o0);
    o1 = o1 > 0.f ? o1 : expm1f(o1);
    float v0 = xv.x + o0, v1 = xv.y + o1;
    float2 ov; ov.x = v0; ov.y = v1;
    *(float2*)(x2 + (size_t)row * HID + c2) = ov;
    // in-register LN2
    float s = v0 + v1;
    #pragma unroll
    for (int o = 32; o > 0; o >>= 1) s += __shfl_xor(s, o, 64);
    float m = s * (1.0f / HID);
    float d0 = v0 - m, d1 = v1 - m;
    float q = d0 * d0 + d1 * d1;
    #pragma unroll
    for (int o = 32; o > 0; o >>= 1) q += __shfl_xor(q, o, 64);
    float rsv = rsqrtf(q * (1.0f / HID) + 1e-5f);
    float2 wv = *(const float2*)(n2w + c2);
    float2 b2v = *(const float2*)(n2b + c2);
    unsigned pk = (unsigned)f2bf(d0 * rsv * wv.x + b2v.x)
                | ((unsigned)f2bf(d1 * rsv * wv.y + b2v.y) << 16);
    *(unsigned*)(hb + (size_t)row * HID + c2) = pk;
}

// ---------------------------------------------------------------------------
// Single-pass message accumulation over TILED xp (standalone, modes 1).
// ---------------------------------------------------------------------------
__global__ __launch_bounds__(256)
void msg1_kernel(const int* offs2, const int* rs_arr, const float* wgt,
                 const u16* xp, float* acc, int NN) {
    int n = blockIdx.x * 4 + (threadIdx.x >> 6);
    if (n >= NN) return;
    int lane = threadIdx.x & 63;
    int half = lane >> 5;
    int co = (lane & 31) << 1;
    int h = lane >> 4;
    int p0 = offs2[n * RR], p1 = offs2[n * RR + RR];
    float a0 = 0.f, a1 = 0.f;
    int p = p0;
    for (; p + 4 <= p1; p += 4) {
        unsigned v0 = (unsigned)rs_arr[p + 0];
        unsigned v1 = (unsigned)rs_arr[p + 1];
        unsigned v2 = (unsigned)rs_arr[p + 2];
        unsigned v3 = (unsigned)rs_arr[p + 3];
        unsigned s0 = v0 & 0xFFFFFFu, s1 = v1 & 0xFFFFFFu;
        unsigned s2 = v2 & 0xFFFFFFu, s3 = v3 & 0xFFFFFFu;
        unsigned z0 = *(const unsigned*)(xp
            + (((size_t)(s0 >> 6) * 16 + ((v0 >> 24) << 1) + half) << 12)
            + ((s0 & 63) << 6) + co);
        unsigned z1 = *(const unsigned*)(xp
            + (((size_t)(s1 >> 6) * 16 + ((v1 >> 24) << 1) + half) << 12)
            + ((s1 & 63) << 6) + co);
        unsigned z2 = *(const unsigned*)(xp
            + (((size_t)(s2 >> 6) * 16 + ((v2 >> 24) << 1) + half) << 12)
            + ((s2 & 63) << 6) + co);
        unsigned z3 = *(const unsigned*)(xp
            + (((size_t)(s3 >> 6) * 16 + ((v3 >> 24) << 1) + half) << 12)
            + ((s3 & 63) << 6) + co);
        float w0 = wgt[(size_t)(p + 0) * NH + h];
        float w1 = wgt[(size_t)(p + 1) * NH + h];
        float w2 = wgt[(size_t)(p + 2) * NH + h];
        float w3 = wgt[(size_t)(p + 3) * NH + h];
        a0 += w0 * bf2f((u16)z0) + w1 * bf2f((u16)z1)
            + w2 * bf2f((u16)z2) + w3 * bf2f((u16)z3);
        a1 += w0 * bf2f((u16)(z0 >> 16)) + w1 * bf2f((u16)(z1 >> 16))
            + w2 * bf2f((u16)(z2 >> 16)) + w3 * bf2f((u16)(z3 >> 16));
    }
    for (; p < p1; p++) {
        unsigned v = (unsigned)rs_arr[p];
        unsigned s = v & 0xFFFFFFu;
        unsigned z = *(const unsigned*)(xp
            + (((size_t)(s >> 6) * 16 + ((v >> 24) << 1) + half) << 12)
            + ((s & 63) << 6) + co);
        float wv = wgt[(size_t)p * NH + h];
        a0 += wv * bf2f((u16)z);
        a1 += wv * bf2f((u16)(z >> 16));
    }
    float2 o; o.x = a0; o.y = a1;
    *(float2*)(acc + (size_t)n * HID + (lane << 1)) = o;
}

// ---------------------------------------------------------------------------
// Multi-pass fallback (nrel < RR).
// ---------------------------------------------------------------------------
__global__ void msg2_kernel(const int* offs2, const int* rs_arr, const float* wgt,
                            const u16* xp, float* acc, int rc, int nrel, int ldx,
                            int NN, int E) {
    int n = blockIdx.x;
    int c = threadIdx.x, h = c >> 5;
    int p0 = offs2[n * RR + rc], p1 = offs2[n * RR + rc + nrel];
    if (p0 >= p1) return;
    float av = acc[(size_t)n * HID + c];
    for (int p = p0; p < p1; p++) {
        unsigned v = (unsigned)rs_arr[p];
        int r = (v >> 24) - rc;
        int s = v & 0xFFFFFF;
        av += wgt[(size_t)p * NH + h] * bf2f(xp[(size_t)s * ldx + r * HID + c]);
    }
    acc[(size_t)n * HID + c] = av;
}

// ---------------------------------------------------------------------------
extern "C" void kernel_launch(void* const* d_in, const int* in_sizes, int n_in,
                              void* d_out, int out_size, void* d_ws, size_t ws_size,
                              hipStream_t stream) {
    const float* x        = (const float*)d_in[0];
    const float* w        = (const float*)d_in[1];
    const float* rootw    = (const float*)d_in[2];
    const float* emb      = (const float*)d_in[3];
    const float* att_src  = (const float*)d_in[4];
    const float* att_dst  = (const float*)d_in[5];
    const float* att_edge = (const float*)d_in[6];
    const float* bias     = (const float*)d_in[7];
    const float* n1w      = (const float*)d_in[8];
    const float* n1b      = (const float*)d_in[9];
    const float* n2w      = (const float*)d_in[10];
    const float* n2b      = (const float*)d_in[11];
    const float* w1       = (const float*)d_in[12];
    const float* b1       = (const float*)d_in[13];
    const float* w2       = (const float*)d_in[14];
    const float* b2       = (const float*)d_in[15];
    const int* ei = (const int*)d_in[16];
    const int* et = (const int*)d_in[17];

    int NN = in_sizes[0] / HID;         // 50000
    int R  = in_sizes[1] / (HID * HID); // 8
    int E  = in_sizes[17];              // 800000
    int NR = NN * RR;
    int NBK = (NN + (1 << NB_SH) - 1) >> NB_SH;
    int gxN = (NN + 63) / 64;
    int Mpad = gxN * 64;

    // ---- arena ------------------------------------------------------------
    char* p = (char*)d_ws;
    auto alloc = [&](size_t bytes) -> char* {
        char* q = p; p += (bytes + 255) & ~(size_t)255; return q;
    };
    int* offs2   = (int*)alloc((size_t)(NR + 1) * 4);
    int* rs_arr  = (int*)alloc((size_t)E * 4);
    u16* WTw   = (u16*)alloc((size_t)R * HID * HID * 2);
    u16* rootT = (u16*)alloc((size_t)HID * HID * 2);
    u16* W1T   = (u16*)alloc((size_t)FFD * HID * 2);
    u16* W2T   = (u16*)alloc((size_t)HID * FFD * 2);
    u16* Vsd   = (u16*)alloc((size_t)64 * HID * 2);
    float* ae  = (float*)alloc((size_t)R * NH * 4);
    float* mu1 = (float*)alloc((size_t)NN * 4);
    float* rs1 = (float*)alloc((size_t)NN * 4);
    float* mu2 = (float*)alloc((size_t)NN * 4);
    float* rs2 = (float*)alloc((size_t)NN * 4);
    float* asad   = (float*)alloc((size_t)NN * 64 * 4);
    float* invden = (float*)alloc((size_t)NN * NH * 4);
    float* wgt    = (float*)alloc((size_t)E * NH * 4);
    float* acc    = (float*)alloc((size_t)NN * HID * 4);

    // CSR-build scratch aliases the (not-yet-live) wgt buffer (12.8MB).
    int nbScan = (NR + SCAN_B - 1) / SCAN_B;
    int* deg2    = (int*)wgt;
    int* curpos2 = deg2 + NR;
    int* bsum    = curpos2 + NR;
    int* bcnt    = bsum + nbScan + 1;
    u64* tmp     = (u64*)(((size_t)(bcnt + NBK * 16) + 7) & ~(size_t)7);

    // Tiered layout: 2 = fused (separate hbuf), 1 = serial single, 0 = multi.
    size_t usedFixed = (size_t)(p - (char*)d_ws);
    size_t xpTiled = (size_t)Mpad * HID * RR * 2;
    size_t hbufSz  = (size_t)NN * HID * 2;
    int mode; int nrel = RR;
    u16 *xp, *hbuf;
    if (ws_size >= usedFixed + hbufSz + xpTiled + 512) {
        mode = 2;
        hbuf = (u16*)alloc(hbufSz);
        xp = (u16*)alloc(xpTiled);
    } else if (ws_size >= usedFixed + xpTiled + 256) {
        mode = 1;
        hbuf = (u16*)asad;
        xp = (u16*)alloc(xpTiled);
    } else {
        mode = 0;
        nrel = 1;
        for (int t = 4; t > 1; t >>= 1) {
            if (ws_size >= usedFixed + (size_t)NN * HID * t * 2 + 256) { nrel = t; break; }
        }
        hbuf = (u16*)asad;
        xp = (u16*)alloc((size_t)NN * HID * nrel * 2);
    }
    u16* u_ch = xp;                   // alias: FFN intermediate
    u16* rootp = (u16*)asad;          // alias: asad dead after wgt (mode 2)
    float* x2 = (float*)d_out;

    size_t used = (size_t)(p - (char*)d_ws);
    if (used > ws_size) {
        zeroout_kernel<<<(out_size + 255) / 256, 256, 0, stream>>>((float*)d_out, out_size);
        return;
    }

    // ---- phase 0: init, stats, weights, CSR scan --------------------------
    int initN = (mode != 0) ? (NR > NBK * 16 ? NR : NBK * 16) : NN * HID;
    init_kernel<<<(initN + 255) / 256, 256, 0, stream>>>(acc, deg2, bcnt, NN, NBK,
                                                         mode == 0 ? 1 : 0);
    stats_kernel<<<(NN + 3) / 4, 256, 0, stream>>>(x, mu1, rs1, NN);
    int nT = R * HID * HID + HID * HID + FFD * HID + HID * FFD;
    transpose_kernel<<<(nT + 255) / 256, 256, 0, stream>>>(w, rootw, w1, w2,
                                                           WTw, rootT, W1T, W2T, R);
    vsd_kernel<<<(64 * HID + 255) / 256, 256, 0, stream>>>(w, att_src, att_dst, Vsd, R);
    ae_kernel<<<1, 64, 0, stream>>>(emb, att_edge, ae, R);
    deg_kernel<<<(E + 255) / 256, 256, 0, stream>>>(ei, et, deg2, E, NN);
    scan1_kernel<<<nbScan, SCAN_B, 0, stream>>>(deg2, offs2, bsum, NR);
    scan2_kernel<<<1, SCAN_B, 0, stream>>>(bsum, nbScan);
    scan3_kernel<<<nbScan, SCAN_B, 0, stream>>>(offs2, curpos2, bsum, NR, nbScan);

    int hB = (NN * (HID / 8) + 255) / 256;
    int fB = (E + 255) / 256;
    int wB = (NN + 3) / 4;

    if (mode == 2) {
        fused1_kernel<<<gxN + hB + fB, 256, 0, stream>>>(
            x, mu1, rs1, n1w, n1b, Vsd, asad, hbuf,
            ei, et, offs2, bcnt, tmp, E, NN, gxN, hB);
        fillB_kernel<<<NBK, 256, 0, stream>>>(tmp, offs2, curpos2, rs_arr, NN);
        int projB = gxN * 2;
        fused2_kernel<<<projB + wB, 256, 0, stream>>>(
            hbuf, WTw, xp, offs2, rs_arr, asad, ae, wgt, invden, NN, gxN, projB);
        // fused3: rootp (into dead asad) || msg1
        fused3_kernel<<<2 * gxN + wB, 256, 0, stream>>>(
            hbuf, rootT, rootp, offs2, rs_arr, wgt, xp, acc, NN, gxN);
        // epi2: EPI1 + stats2 + hnorm2 in one pass
        epi2_kernel<<<wB, 256, 0, stream>>>(
            rootp, acc, invden, bias, x, x2, n2w, n2b, hbuf, NN);
    } else {
        fillA_kernel<<<fB, 256, 0, stream>>>(ei, et, offs2, bcnt, tmp, E, NN);
        fillB_kernel<<<NBK, 256, 0, stream>>>(tmp, offs2, curpos2, rs_arr, NN);
        gemm_kernel<0, 5><<<dim3(gxN, 1), 256, 0, stream>>>(
            x, mu1, rs1, n1w, n1b, Vsd, asad,
            nullptr, nullptr, nullptr, nullptr, NN, 64, HID, 0, 0);
        wgt_kernel<<<wB, 256, 0, stream>>>(
            offs2, rs_arr, asad, ae, wgt, invden, NN, E);
        hnorm_kernel<<<hB, 256, 0, stream>>>(x, mu1, rs1, n1w, n1b, hbuf, NN);
        if (mode == 1) {
            gemmy_kernel<0, 1><<<dim3(gxN, 2), 256, 0, stream>>>(
                hbuf, WTw, xp, nullptr, NN, HID * RR, 0, 0, 8);
            msg1_kernel<<<wB, 256, 0, stream>>>(offs2, rs_arr, wgt, xp, acc, NN);
        } else {
            for (int rc = 0; rc < RR; rc += nrel) {
                gemm_kernel<2, 0><<<dim3(gxN, (HID * nrel) / 64), 256, 0, stream>>>(
                    hbuf, nullptr, nullptr, nullptr, nullptr, WTw + (size_t)rc * HID * HID,
                    xp, nullptr, nullptr, nullptr, nullptr, NN, HID * nrel, HID, 0, 0);
                msg2_kernel<<<NN, HID, 0, stream>>>(offs2, rs_arr, wgt, xp, acc,
                                                    rc, nrel, HID * nrel, NN, E);
            }
        }
        gemm_kernel<2, 1><<<dim3(gxN, HID / 64), 256, 0, stream>>>(
            hbuf, nullptr, nullptr, nullptr, nullptr, rootT, x2, bias, acc, x, invden,
            NN, HID, HID, 0, 0);
        stats_kernel<<<wB, 256, 0, stream>>>(x2, mu2, rs2, NN);
        hnorm_kernel<<<hB, 256, 0, stream>>>(x2, mu2, rs2, n2w, n2b, hbuf, NN);
    }

    // ---- FFN --------------------------------------------------------------
    int nchunk = (mode != 0) ? 1 : (nrel >= 4 ? 1 : (nrel == 2 ? 2 : 4));
    int NCH = (NN + nchunk - 1) / nchunk;
    for (int j = 0; j < nchunk; j++) {
        int r0 = j * NCH;
        int Mc = NN - r0; if (Mc > NCH) Mc = NCH;
        if (Mc <= 0) continue;
        int gxc = (Mc + 63) / 64;
        gemmy_kernel<2, 0><<<dim3(gxc, 2), 256, 0, stream>>>(
            hbuf, W1T, u_ch, b1, Mc, FFD, r0, 0, 4);
        gemm_kernel<2, 3><<<dim3(gxc, HID / 64), 256, 0, stream>>>(
            u_ch, nullptr, nullptr, nullptr, nullptr, W2T, (float*)d_out, b2,
            nullptr, x2, nullptr, Mc, HID, FFD, 0, r0);
    }
}